// Round 9
// baseline (5929.152 us; speedup 1.0000x reference)
//
#include <hip/hip_runtime.h>
#include <hip/hip_bf16.h>

typedef __bf16 bf16x8 __attribute__((ext_vector_type(8)));
typedef float f32x4 __attribute__((ext_vector_type(4)));

constexpr int NB   = 512;   // batch
constexpr int NT   = 128;   // timesteps
constexpr int ND   = 128;   // input dim
constexpr int NH   = 512;   // hidden
constexpr int NMEM = 64;    // attention memory
constexpr int KKA  = 640;   // h(512)+x(128)
constexpr int KKB  = 1152;  // h(512)+x(128)+s(512)

// barrier region layout (u32 indices)
constexpr int BAR_CNT = 0;        // [8] per-XCD member counts
constexpr int BAR_GB  = 64;       // [257] stride 32: global fallback/setup barrier flags
constexpr int BAR_MFL = 8448;     // [8][32] stride 16: per-XCD member flags
constexpr int BAR_DFL = 12800;    // [8] stride 32: per-XCD done flags
constexpr int BAR_TOT = 16384;

__device__ __forceinline__ float sigm_(float x) { return 1.f / (1.f + expf(-x)); }

// ---- atomic helpers ----
__device__ __forceinline__ unsigned ld_rlx_sys(const unsigned* p) {
    return __hip_atomic_load(p, __ATOMIC_RELAXED, __HIP_MEMORY_SCOPE_SYSTEM);
}
__device__ __forceinline__ unsigned ld_acq_sys(const unsigned* p) {
    return __hip_atomic_load(p, __ATOMIC_ACQUIRE, __HIP_MEMORY_SCOPE_SYSTEM);
}
__device__ __forceinline__ void st_rel_sys(unsigned* p, unsigned v) {
    __hip_atomic_store(p, v, __ATOMIC_RELEASE, __HIP_MEMORY_SCOPE_SYSTEM);
}
__device__ __forceinline__ unsigned ld_rlx_agt(const unsigned* p) {
    return __hip_atomic_load(p, __ATOMIC_RELAXED, __HIP_MEMORY_SCOPE_AGENT);
}
__device__ __forceinline__ unsigned ld_acq_agt(const unsigned* p) {
    return __hip_atomic_load(p, __ATOMIC_ACQUIRE, __HIP_MEMORY_SCOPE_AGENT);
}
__device__ __forceinline__ void st_rlx_agt(unsigned* p, unsigned v) {
    __hip_atomic_store(p, v, __ATOMIC_RELAXED, __HIP_MEMORY_SCOPE_AGENT);
}

// ---------------- prep kernels ----------------

__global__ void k_shufA(const float* __restrict__ Wh, const float* __restrict__ Wx,
                        __hip_bfloat16* __restrict__ WA_shuf) {
    int nb = blockIdx.x / 20, kk = blockIdx.x % 20;
    int lane = threadIdx.x;
    int n = nb * 16 + (lane & 15);
    int kbase = kk * 32 + (lane >> 4) * 8;
    size_t o = ((size_t)blockIdx.x * 64 + lane) * 8;
    for (int e = 0; e < 8; ++e) {
        int k = kbase + e;
        float v = (k < 512) ? Wh[(size_t)k * NH + n]
                            : Wx[(size_t)(k - 512) * NH + n];
        WA_shuf[o + e] = __float2bfloat16(v);
    }
}

__global__ void k_shufB(const float* __restrict__ Wh, const float* __restrict__ Wx,
                        const float* __restrict__ Ws, __hip_bfloat16* __restrict__ WB_shuf) {
    int idx = blockIdx.x;                 // jb*180 + g*36 + kk
    int kk = idx % 36, g = (idx / 36) % 5, jb = idx / 180;
    int lane = threadIdx.x;
    int j = jb * 16 + (lane & 15);
    int kbase = kk * 32 + (lane >> 4) * 8;
    size_t o = ((size_t)idx * 64 + lane) * 8;
    for (int e = 0; e < 8; ++e) {
        int k = kbase + e;
        float v;
        if (k < 512)      v = Wh[(size_t)(g + 1) * NH * NH + (size_t)k * NH + j];
        else if (k < 640) v = Wx[(size_t)(g + 1) * ND * NH + (size_t)(k - 512) * NH + j];
        else              v = Ws[(size_t)g * NH * NH + (size_t)(k - 640) * NH + j];
        WB_shuf[o + e] = __float2bfloat16(v);
    }
}

__global__ void k_shufW(const float* __restrict__ Wah, __hip_bfloat16* __restrict__ Wah_shuf) {
    int nb = blockIdx.x / 16, kk = blockIdx.x % 16;
    int lane = threadIdx.x;
    int j = nb * 16 + (lane & 15);
    int kbase = kk * 32 + (lane >> 4) * 8;
    size_t o = ((size_t)blockIdx.x * 64 + lane) * 8;
    for (int e = 0; e < 8; ++e)
        Wah_shuf[o + e] = __float2bfloat16(Wah[(size_t)(kbase + e) * NH + j]);
}

__global__ void k_biases(const float* bh_lin, const float* bx_lin, const float* bst,
                         const float* bs_lin, const float* bg,
                         const float* b_Wh, const float* b_We, const float* b_Wg, const float* bh_p,
                         float* bias_s, float* bias_g, float* bias_fin) {
    int j = threadIdx.x;
    bias_s[j] = bh_lin[j] + bx_lin[j] + bst[j] + bg[j];
    for (int g = 0; g < 5; ++g)
        bias_g[g * NH + j] = bh_lin[(g + 1) * NH + j] + bx_lin[(g + 1) * NH + j] +
                             bs_lin[g * NH + j] + bg[(g + 1) * NH + j];
    bias_fin[j] = b_Wh[j] + b_We[j] + b_Wg[j] + bh_p[j];
}

// per-row init: Dt, A_big[0] (h=0, x=x_0); block 0 zeroes barrier region
__global__ void k_init(const float* __restrict__ X_seq, float* __restrict__ Dt,
                       __hip_bfloat16* __restrict__ A_big, unsigned* __restrict__ bar) {
    int b = blockIdx.x, tid = threadIdx.x;
    if (b == 0) for (int i = tid; i < BAR_TOT; i += 256) bar[i] = 0;
    if (tid < NT) Dt[tid * NB + b] = X_seq[((size_t)b * NT + tid) * (ND + 1) + ND];
    for (int c = tid; c < KKB; c += 256) {
        float v = 0.f;
        if (c >= 512 && c < 640) v = X_seq[(size_t)b * NT * (ND + 1) + (c - 512)];
        A_big[(size_t)b * KKB + c] = __float2bfloat16(v);
    }
}

// ---------------- global fallback barrier (512-thread safe) ----------------
__device__ __forceinline__ void gbar2(unsigned* __restrict__ gb, int wg, unsigned gen) {
    __syncthreads();
    const int tid = threadIdx.x;
    if (tid == 0) st_rel_sys(&gb[wg * 32], gen);
    if (wg == 0) {
        if (tid < 256) {
            while (ld_rlx_sys(&gb[tid * 32]) < gen) {}
            (void)ld_acq_sys(&gb[tid * 32]);
        }
        __syncthreads();
        if (tid == 0) st_rel_sys(&gb[256 * 32], gen);
    }
    if (tid == 0) {
        while (ld_rlx_sys(&gb[256 * 32]) < gen) {}
        (void)ld_acq_sys(&gb[256 * 32]);
    }
    __syncthreads();
}

// ---------------- intra-XCD barrier (local mode) ----------------
__device__ __forceinline__ void gbarL(unsigned* __restrict__ bar, unsigned xcd, unsigned rank,
                                      unsigned gen) {
    const int tid = threadIdx.x;
    __syncthreads();                                   // data ack'd into local L2
    if (tid == 0) st_rlx_agt(&bar[BAR_MFL + (xcd * 32 + rank) * 16], gen);
    if (rank == 0) {
        if (tid < 32) { while (ld_rlx_agt(&bar[BAR_MFL + (xcd * 32 + tid) * 16]) < gen) {} }
        __syncthreads();
        if (tid == 0) st_rlx_agt(&bar[BAR_DFL + xcd * 32], gen);
    }
    if (tid == 0) {
        while (ld_rlx_agt(&bar[BAR_DFL + xcd * 32]) < gen) {}
        (void)ld_acq_agt(&bar[BAR_DFL + xcd * 32]);    // inv L1 (CU-wide)
    }
    __syncthreads();
}

// ---------------- persistent LSTM kernel: row-split by XCD, 8 waves/WG ----------------
// Waves 0-3 ("E-waves"): phase A + phase-B gates {z,o} + full epilogue (c_reg,
// exact same thread->(row,col) mapping as round 8). Waves 4-7 ("G-waves"):
// x-staging during phase A, phase-B gates {f,i,T}; accumulators passed to
// E-waves via LDS as exact f32 (no accumulation reorder anywhere).

__global__ __launch_bounds__(512, 1) void lstm_coop(
    const float* __restrict__ X_seq, const float* __restrict__ Dt,
    const __hip_bfloat16* __restrict__ WA_shuf, const __hip_bfloat16* __restrict__ WB_shuf,
    const float* __restrict__ bias_s, const float* __restrict__ bias_g,
    const float* __restrict__ Wst,
    __hip_bfloat16* __restrict__ A_big,       // [2][NB][KKB]
    float* __restrict__ c_last, float* __restrict__ s_f32, float* __restrict__ h_last,
    __hip_bfloat16* __restrict__ hist,        // [NMEM][NB][NH]
    unsigned* __restrict__ bar)
{
    const int wg = blockIdx.x;       // 0..255
    const int tid = threadIdx.x;     // 0..511
    const int wv = tid >> 6;         // 0..7
    const int lane = tid & 63;
    const int l15 = lane & 15, lhi = lane >> 4;
    const int rt  = wv & 3;          // row-tile 0..3
    const int grp = wv >> 2;         // 0 = E-waves, 1 = G-waves

    __shared__ f32x4 lds_g[4][3][64];   // G-wave accumulators (gates f,i,T)

    // ---- one-time XCD membership registration ----
    __shared__ unsigned sh_meta[2];
    __shared__ unsigned sh_cnt[8];
    if (tid == 0) {
        unsigned xcc;
        asm volatile("s_getreg_b32 %0, hwreg(HW_REG_XCC_ID)" : "=s"(xcc));
        xcc &= 7u;
        unsigned r = __hip_atomic_fetch_add(&bar[BAR_CNT + xcc], 1u,
                                            __ATOMIC_RELAXED, __HIP_MEMORY_SCOPE_AGENT);
        sh_meta[0] = xcc; sh_meta[1] = r;
    }
    __syncthreads();
    gbar2(bar + BAR_GB, wg, 1u);                 // counts final + visible
    if (tid < 8) sh_cnt[tid] = ld_rlx_sys(&bar[BAR_CNT + tid]);
    __syncthreads();
    bool local_ok = true;
    #pragma unroll
    for (int j = 0; j < 8; ++j) if (sh_cnt[j] != 32u) local_ok = false;

    const unsigned xcd  = local_ok ? sh_meta[0] : (unsigned)(wg & 7);
    const unsigned rank = local_ok ? sh_meta[1] : (unsigned)(wg >> 3);
    const int row_base  = (int)xcd * 64;         // this group owns rows [row_base, +64)

    const int colj = (int)rank * 16 + l15;       // output column

    const float ebs  = bias_s[colj];
    const float ewst = Wst[colj];
    float bgc[5];
    #pragma unroll
    for (int g = 0; g < 5; ++g) bgc[g] = bias_g[g * NH + colj];

    const __hip_bfloat16* wa_base = WA_shuf + (size_t)rank * 20 * 512 + lane * 8;
    const __hip_bfloat16* wb_base = WB_shuf + (size_t)rank * 5 * 36 * 512 + lane * 8;

    f32x4 c_reg = {0.f, 0.f, 0.f, 0.f};          // E-waves only (rows rt*16.., col colj)

    for (int t = 0; t < NT; ++t) {
        const int buf = t & 1;
        const __hip_bfloat16* A = A_big + (size_t)buf * NB * KKB;
        __hip_bfloat16* An = A_big + (size_t)(buf ^ 1) * NB * KKB;
        __hip_bfloat16* Aw = A_big + (size_t)buf * NB * KKB;

        // ---- phase A: E-waves compute s; G-waves stage x_{t+1}
        if (grp == 0) {
            f32x4 acc = {0.f, 0.f, 0.f, 0.f};
            const __hip_bfloat16* arow = A + (size_t)(row_base + rt * 16 + l15) * KKB + lhi * 8;
            #pragma unroll 4
            for (int kk = 0; kk < 20; ++kk) {
                bf16x8 af = *reinterpret_cast<const bf16x8*>(arow + kk * 32);
                bf16x8 bfv = *reinterpret_cast<const bf16x8*>(wa_base + kk * 512);
                acc = __builtin_amdgcn_mfma_f32_16x16x32_bf16(af, bfv, acc, 0, 0, 0);
            }
            #pragma unroll
            for (int r = 0; r < 4; ++r) {
                int row = row_base + rt * 16 + lhi * 4 + r;
                float s = tanhf(acc[r] + ebs + Dt[t * NB + row] * ewst);
                s_f32[row * NH + colj] = s;
                Aw[(size_t)row * KKB + 640 + colj] = __float2bfloat16(s);
            }
        } else if (t < NT - 1) {
            // stage x_{t+1}: 32 WGs x 256 G-threads = 8192 elems (64 rows x 128 d)
            int idx = (int)rank * 256 + (tid - 256);
            int rr = idx >> 7, d = idx & 127;
            int row = row_base + rr;
            float xv = X_seq[((size_t)row * NT + (t + 1)) * (ND + 1) + d];
            An[(size_t)row * KKB + 512 + d] = __float2bfloat16(xv);
        }
        if (local_ok) gbarL(bar, xcd, rank, (unsigned)(2 * t + 1));
        else          gbar2(bar + BAR_GB, wg, (unsigned)(2 * t + 2));

        // ---- phase B: gate-split MFMA (E: gates 3,4; G: gates 0,1,2)
        {
            f32x4 acc[3] = {};
            const int g0 = (grp == 0) ? 3 : 0;
            const int ng = (grp == 0) ? 2 : 3;
            const __hip_bfloat16* arow = A + (size_t)(row_base + rt * 16 + l15) * KKB + lhi * 8;
            for (int kk = 0; kk < 36; ++kk) {
                bf16x8 af = *reinterpret_cast<const bf16x8*>(arow + kk * 32);
                #pragma unroll
                for (int gi = 0; gi < 3; ++gi) {
                    if (gi < ng) {
                        bf16x8 bfv = *reinterpret_cast<const bf16x8*>(
                            wb_base + ((g0 + gi) * 36 + kk) * 512);
                        acc[gi] = __builtin_amdgcn_mfma_f32_16x16x32_bf16(af, bfv, acc[gi], 0, 0, 0);
                    }
                }
            }
            if (grp == 1) {
                #pragma unroll
                for (int gi = 0; gi < 3; ++gi) lds_g[rt][gi][lane] = acc[gi];
            }
            __syncthreads();
            if (grp == 0) {
                f32x4 a_f = lds_g[rt][0][lane];
                f32x4 a_i = lds_g[rt][1][lane];
                f32x4 a_T = lds_g[rt][2][lane];
                #pragma unroll
                for (int r = 0; r < 4; ++r) {
                    int row = row_base + rt * 16 + lhi * 4 + r;
                    float f  = sigm_(a_f[r] + bgc[0]);
                    float i  = sigm_(a_i[r] + bgc[1]);
                    float Tg = sigm_(a_T[r] + bgc[2]);
                    float z  = tanhf(acc[0][r] + bgc[3]);
                    float o  = sigm_(acc[1][r] + bgc[4]);
                    float sv = s_f32[row * NH + colj];
                    float cn = f * c_reg[r] + i * z + Tg * sv;
                    c_reg[r] = cn;
                    float hn = o * tanhf(cn);
                    An[(size_t)row * KKB + colj] = __float2bfloat16(hn);
                    if (t >= NT - NMEM)
                        hist[((size_t)(t - (NT - NMEM)) * NB + row) * NH + colj] = __float2bfloat16(hn);
                    if (t == NT - 1) {
                        h_last[row * NH + colj] = hn;
                        c_last[row * NH + colj] = cn;
                    }
                }
            }
        }
        if (local_ok) gbarL(bar, xcd, rank, (unsigned)(2 * t + 2));
        else          gbar2(bar + BAR_GB, wg, (unsigned)(2 * t + 3));
    }
}

// ---------------- attention + head (unchanged) ----------------

__global__ void k_qa(const float* __restrict__ h_last, const float* __restrict__ c_last,
                     const float* __restrict__ Waq, const float* __restrict__ baq,
                     float* __restrict__ qa) {
    __shared__ float qs[8][1024];
    int b0 = blockIdx.x * 8;
    for (int idx = threadIdx.x; idx < 8 * 1024; idx += 512) {
        int bb = idx >> 10, k = idx & 1023;
        qs[bb][k] = (k < 512) ? h_last[(b0 + bb) * NH + k] : c_last[(b0 + bb) * NH + (k - 512)];
    }
    __syncthreads();
    int j = threadIdx.x;
    float acc[8] = {};
    for (int k = 0; k < 1024; ++k) {
        float w = Waq[(size_t)k * NH + j];
        #pragma unroll
        for (int bb = 0; bb < 8; ++bb) acc[bb] += qs[bb][k] * w;
    }
    float bq = baq[j];
    for (int bb = 0; bb < 8; ++bb) qa[(b0 + bb) * NH + j] = acc[bb] + bq;
}

__global__ void k_scores(const __hip_bfloat16* __restrict__ hist,
                         const __hip_bfloat16* __restrict__ Wah_shuf,
                         const float* __restrict__ qa, const float* __restrict__ bah,
                         const float* __restrict__ vt, float* __restrict__ score_part) {
    int rt = blockIdx.x, jt = blockIdx.y;
    int tid = threadIdx.x, wv = tid >> 6, lane = tid & 63;
    int l15 = lane & 15, lhi = lane >> 4;
    int R0 = rt * 64 + wv * 16;
    f32x4 acc[4] = {};
    const __hip_bfloat16* arow = hist + (size_t)(R0 + l15) * NH + lhi * 8;
    const __hip_bfloat16* bbase = Wah_shuf + lane * 8;
    for (int kk = 0; kk < 16; ++kk) {
        bf16x8 af = *reinterpret_cast<const bf16x8*>(arow + kk * 32);
        #pragma unroll
        for (int f = 0; f < 4; ++f) {
            int nb = jt * 4 + f;
            bf16x8 bfv = *reinterpret_cast<const bf16x8*>(bbase + (size_t)(nb * 16 + kk) * 512);
            acc[f] = __builtin_amdgcn_mfma_f32_16x16x32_bf16(af, bfv, acc[f], 0, 0, 0);
        }
    }
    float part[4] = {};
    #pragma unroll
    for (int r = 0; r < 4; ++r) {
        int R = R0 + lhi * 4 + r;
        int b = R & (NB - 1);
        #pragma unroll
        for (int f = 0; f < 4; ++f) {
            int j = (jt * 4 + f) * 16 + l15;
            float v = acc[f][r] + qa[b * NH + j] + bah[j];
            part[r] += tanhf(v) * vt[j];
        }
    }
    #pragma unroll
    for (int m = 1; m <= 8; m <<= 1)
        #pragma unroll
        for (int r = 0; r < 4; ++r) part[r] += __shfl_xor(part[r], m);
    if (l15 == 0)
        #pragma unroll
        for (int r = 0; r < 4; ++r)
            score_part[(size_t)jt * (NMEM * NB) + R0 + lhi * 4 + r] = part[r];
}

__global__ void k_softmax_e(const float* __restrict__ score_part,
                            const __hip_bfloat16* __restrict__ hist,
                            float* __restrict__ e_buf) {
    int b = blockIdx.x, m = threadIdx.x;  // 64 threads
    float sc = 0.f;
    for (int p = 0; p < 8; ++p) sc += score_part[(size_t)p * (NMEM * NB) + m * NB + b];
    float mx = sc;
    for (int off = 32; off; off >>= 1) mx = fmaxf(mx, __shfl_xor(mx, off));
    float ex = expf(sc - mx);
    float sm = ex;
    for (int off = 32; off; off >>= 1) sm += __shfl_xor(sm, off);
    float alpha = ex / sm;
    __shared__ float al[64];
    al[m] = alpha;
    __syncthreads();
    for (int j0 = 0; j0 < NH; j0 += 64) {
        int j = j0 + m;
        float acc = 0.f;
        for (int mm = 0; mm < 64; ++mm)
            acc += al[mm] * __bfloat162float(hist[((size_t)mm * NB + b) * NH + j]);
        e_buf[b * NH + j] = acc;
    }
}

__global__ void k_final(const float* __restrict__ h_last, const float* __restrict__ e_buf,
                        const float* __restrict__ X_seq, const float* __restrict__ W_h,
                        const float* __restrict__ We, const float* __restrict__ Wg,
                        const float* __restrict__ bias_fin, float* __restrict__ h_fin) {
    __shared__ float hs[8][512], es[8][512], xs[8][128];
    int b0 = blockIdx.x * 8;
    for (int idx = threadIdx.x; idx < 8 * 512; idx += 512) {
        int bb = idx >> 9, k = idx & 511;
        hs[bb][k] = h_last[(b0 + bb) * NH + k];
        es[bb][k] = e_buf[(b0 + bb) * NH + k];
    }
    for (int idx = threadIdx.x; idx < 8 * 128; idx += 512) {
        int bb = idx >> 7, d = idx & 127;
        xs[bb][d] = X_seq[((size_t)(b0 + bb) * NT + (NT - 1)) * (ND + 1) + d];
    }
    __syncthreads();
    int j = threadIdx.x;
    float acc[8];
    float bfv = bias_fin[j];
    #pragma unroll
    for (int bb = 0; bb < 8; ++bb) acc[bb] = bfv;
    for (int k = 0; k < 512; ++k) {
        float w = W_h[(size_t)k * NH + j];
        #pragma unroll
        for (int bb = 0; bb < 8; ++bb) acc[bb] += hs[bb][k] * w;
    }
    for (int k = 0; k < 512; ++k) {
        float w = We[(size_t)k * NH + j];
        #pragma unroll
        for (int bb = 0; bb < 8; ++bb) acc[bb] += es[bb][k] * w;
    }
    for (int d = 0; d < 128; ++d) {
        float w = Wg[(size_t)d * NH + j];
        #pragma unroll
        for (int bb = 0; bb < 8; ++bb) acc[bb] += xs[bb][d] * w;
    }
    for (int bb = 0; bb < 8; ++bb) h_fin[(b0 + bb) * NH + j] = tanhf(acc[bb]);
}

__global__ void k_out(const float* __restrict__ h_fin, const float* __restrict__ Wc,
                      const float* __restrict__ bc, float* __restrict__ out) {
    int b = blockIdx.x, tid = threadIdx.x;  // 256 threads
    float p = 0.f;
    for (int j = tid; j < NH; j += 256) p += h_fin[b * NH + j] * Wc[j];
    for (int off = 32; off; off >>= 1) p += __shfl_xor(p, off);
    __shared__ float red[4];
    if ((tid & 63) == 0) red[tid >> 6] = p;
    __syncthreads();
    if (tid == 0) out[b] = 1.f / (1.f + expf(-(red[0] + red[1] + red[2] + red[3] + bc[0])));
}

// ---------------- launch ----------------

extern "C" void kernel_launch(void* const* d_in, const int* in_sizes, int n_in,
                              void* d_out, int out_size, void* d_ws, size_t ws_size,
                              hipStream_t stream) {
    const float* X_seq  = (const float*)d_in[0];
    const float* Wh     = (const float*)d_in[1];
    const float* bh_lin = (const float*)d_in[2];
    const float* Wx     = (const float*)d_in[3];
    const float* bx_lin = (const float*)d_in[4];
    const float* Wst    = (const float*)d_in[5];
    const float* bst    = (const float*)d_in[6];
    const float* Ws     = (const float*)d_in[7];
    const float* bs_lin = (const float*)d_in[8];
    const float* bg     = (const float*)d_in[9];
    const float* Waq    = (const float*)d_in[10];
    const float* baq    = (const float*)d_in[11];
    const float* Wah    = (const float*)d_in[12];
    const float* bah    = (const float*)d_in[13];
    const float* vt     = (const float*)d_in[14];
    const float* W_h    = (const float*)d_in[15];
    const float* b_Wh   = (const float*)d_in[16];
    const float* We     = (const float*)d_in[17];
    const float* b_We   = (const float*)d_in[18];
    const float* Wg     = (const float*)d_in[19];
    const float* b_Wg   = (const float*)d_in[20];
    const float* bh_p   = (const float*)d_in[21];
    const float* Wc     = (const float*)d_in[22];
    const float* bc     = (const float*)d_in[23];
    float* out = (float*)d_out;

    char* ws = (char*)d_ws;
    size_t off = 0;
    auto alloc = [&](size_t bytes) -> char* {
        char* p = ws + off;
        off = (off + bytes + 255) & ~(size_t)255;
        return p;
    };
    __hip_bfloat16* WA_shuf  = (__hip_bfloat16*)alloc((size_t)KKA * NH * 2);
    __hip_bfloat16* WB_shuf  = (__hip_bfloat16*)alloc((size_t)KKB * 5 * NH * 2);
    __hip_bfloat16* Wah_shuf = (__hip_bfloat16*)alloc((size_t)NH * NH * 2);
    float* bias_s   = (float*)alloc(NH * 4);
    float* bias_g   = (float*)alloc(5 * NH * 4);
    float* bias_fin = (float*)alloc(NH * 4);
    float* Dt       = (float*)alloc((size_t)NT * NB * 4);
    __hip_bfloat16* A_big = (__hip_bfloat16*)alloc((size_t)2 * NB * KKB * 2);
    float* c_last   = (float*)alloc((size_t)NB * NH * 4);
    float* s_f32    = (float*)alloc((size_t)NB * NH * 4);
    float* h_last   = (float*)alloc((size_t)NB * NH * 4);
    __hip_bfloat16* hist = (__hip_bfloat16*)alloc((size_t)NMEM * NB * NH * 2);
    float* qa       = (float*)alloc((size_t)NB * NH * 4);
    float* score_part = (float*)alloc((size_t)8 * NMEM * NB * 4);
    float* e_buf    = (float*)alloc((size_t)NB * NH * 4);
    float* h_fin    = (float*)alloc((size_t)NB * NH * 4);
    unsigned* bar   = (unsigned*)alloc((size_t)BAR_TOT * 4 + 4096);

    // prep
    hipLaunchKernelGGL(k_shufA, dim3(32 * 20), dim3(64), 0, stream, Wh, Wx, WA_shuf);
    hipLaunchKernelGGL(k_shufB, dim3(32 * 5 * 36), dim3(64), 0, stream, Wh, Wx, Ws, WB_shuf);
    hipLaunchKernelGGL(k_shufW, dim3(32 * 16), dim3(64), 0, stream, Wah, Wah_shuf);
    hipLaunchKernelGGL(k_biases, dim3(1), dim3(512), 0, stream,
                       bh_lin, bx_lin, bst, bs_lin, bg, b_Wh, b_We, b_Wg, bh_p,
                       bias_s, bias_g, bias_fin);
    hipLaunchKernelGGL(k_init, dim3(NB), dim3(256), 0, stream, X_seq, Dt, A_big, bar);

    // persistent recurrent kernel (cooperative launch for co-residency guarantee)
    {
        void* args[] = {(void*)&X_seq, (void*)&Dt, (void*)&WA_shuf, (void*)&WB_shuf,
                        (void*)&bias_s, (void*)&bias_g, (void*)&Wst, (void*)&A_big,
                        (void*)&c_last, (void*)&s_f32, (void*)&h_last, (void*)&hist,
                        (void*)&bar};
        hipLaunchCooperativeKernel((void*)lstm_coop, dim3(256), dim3(512), args, 0, stream);
    }

    // attention + head
    hipLaunchKernelGGL(k_qa, dim3(64), dim3(512), 0, stream, h_last, c_last, Waq, baq, qa);
    hipLaunchKernelGGL(k_scores, dim3(512, 8), dim3(256), 0, stream,
                       hist, Wah_shuf, qa, bah, vt, score_part);
    hipLaunchKernelGGL(k_softmax_e, dim3(NB), dim3(64), 0, stream, score_part, hist, e_buf);
    hipLaunchKernelGGL(k_final, dim3(64), dim3(512), 0, stream,
                       h_last, e_buf, X_seq, W_h, We, Wg, bias_fin, h_fin);
    hipLaunchKernelGGL(k_out, dim3(NB), dim3(256), 0, stream, h_fin, Wc, bc, out);
}

// Round 13
// 3861.935 us; speedup vs baseline: 1.5353x; 1.5353x over previous
//
#include <hip/hip_runtime.h>
#include <hip/hip_bf16.h>

typedef __bf16 bf16x8 __attribute__((ext_vector_type(8)));
typedef float f32x4 __attribute__((ext_vector_type(4)));

constexpr int NB   = 512;   // batch
constexpr int NT   = 128;   // timesteps
constexpr int ND   = 128;   // input dim
constexpr int NH   = 512;   // hidden
constexpr int NMEM = 64;    // attention memory
constexpr int KKA  = 640;   // h(512)+x(128)
constexpr int KKB  = 1152;  // h(512)+x(128)+s(512)

// barrier region layout (u32 indices)
constexpr int BAR_CNT = 0;        // [8] per-XCD member counts
constexpr int BAR_GB  = 64;       // [257] stride 32: global fallback/setup barrier flags
constexpr int BAR_MFL = 8448;     // [8][32] stride 16: per-XCD member flags
constexpr int BAR_DFL = 12800;    // [8] stride 32: per-XCD done flags
constexpr int BAR_TOT = 16384;

__device__ __forceinline__ float sigm_(float x) { return 1.f / (1.f + expf(-x)); }

// ---- atomic helpers ----
__device__ __forceinline__ unsigned ld_rlx_sys(const unsigned* p) {
    return __hip_atomic_load(p, __ATOMIC_RELAXED, __HIP_MEMORY_SCOPE_SYSTEM);
}
__device__ __forceinline__ unsigned ld_acq_sys(const unsigned* p) {
    return __hip_atomic_load(p, __ATOMIC_ACQUIRE, __HIP_MEMORY_SCOPE_SYSTEM);
}
__device__ __forceinline__ void st_rel_sys(unsigned* p, unsigned v) {
    __hip_atomic_store(p, v, __ATOMIC_RELEASE, __HIP_MEMORY_SCOPE_SYSTEM);
}
__device__ __forceinline__ unsigned ld_rlx_agt(const unsigned* p) {
    return __hip_atomic_load(p, __ATOMIC_RELAXED, __HIP_MEMORY_SCOPE_AGENT);
}
__device__ __forceinline__ unsigned ld_acq_agt(const unsigned* p) {
    return __hip_atomic_load(p, __ATOMIC_ACQUIRE, __HIP_MEMORY_SCOPE_AGENT);
}
__device__ __forceinline__ void st_rlx_agt(unsigned* p, unsigned v) {
    __hip_atomic_store(p, v, __ATOMIC_RELAXED, __HIP_MEMORY_SCOPE_AGENT);
}

// ---------------- prep kernels ----------------

__global__ void k_shufA(const float* __restrict__ Wh, const float* __restrict__ Wx,
                        __hip_bfloat16* __restrict__ WA_shuf) {
    int nb = blockIdx.x / 20, kk = blockIdx.x % 20;
    int lane = threadIdx.x;
    int n = nb * 16 + (lane & 15);
    int kbase = kk * 32 + (lane >> 4) * 8;
    size_t o = ((size_t)blockIdx.x * 64 + lane) * 8;
    for (int e = 0; e < 8; ++e) {
        int k = kbase + e;
        float v = (k < 512) ? Wh[(size_t)k * NH + n]
                            : Wx[(size_t)(k - 512) * NH + n];
        WA_shuf[o + e] = __float2bfloat16(v);
    }
}

__global__ void k_shufB(const float* __restrict__ Wh, const float* __restrict__ Wx,
                        const float* __restrict__ Ws, __hip_bfloat16* __restrict__ WB_shuf) {
    int idx = blockIdx.x;                 // jb*180 + g*36 + kk
    int kk = idx % 36, g = (idx / 36) % 5, jb = idx / 180;
    int lane = threadIdx.x;
    int j = jb * 16 + (lane & 15);
    int kbase = kk * 32 + (lane >> 4) * 8;
    size_t o = ((size_t)idx * 64 + lane) * 8;
    for (int e = 0; e < 8; ++e) {
        int k = kbase + e;
        float v;
        if (k < 512)      v = Wh[(size_t)(g + 1) * NH * NH + (size_t)k * NH + j];
        else if (k < 640) v = Wx[(size_t)(g + 1) * ND * NH + (size_t)(k - 512) * NH + j];
        else              v = Ws[(size_t)g * NH * NH + (size_t)(k - 640) * NH + j];
        WB_shuf[o + e] = __float2bfloat16(v);
    }
}

__global__ void k_shufW(const float* __restrict__ Wah, __hip_bfloat16* __restrict__ Wah_shuf) {
    int nb = blockIdx.x / 16, kk = blockIdx.x % 16;
    int lane = threadIdx.x;
    int j = nb * 16 + (lane & 15);
    int kbase = kk * 32 + (lane >> 4) * 8;
    size_t o = ((size_t)blockIdx.x * 64 + lane) * 8;
    for (int e = 0; e < 8; ++e)
        Wah_shuf[o + e] = __float2bfloat16(Wah[(size_t)(kbase + e) * NH + j]);
}

__global__ void k_biases(const float* bh_lin, const float* bx_lin, const float* bst,
                         const float* bs_lin, const float* bg,
                         const float* b_Wh, const float* b_We, const float* b_Wg, const float* bh_p,
                         float* bias_s, float* bias_g, float* bias_fin) {
    int j = threadIdx.x;
    bias_s[j] = bh_lin[j] + bx_lin[j] + bst[j] + bg[j];
    for (int g = 0; g < 5; ++g)
        bias_g[g * NH + j] = bh_lin[(g + 1) * NH + j] + bx_lin[(g + 1) * NH + j] +
                             bs_lin[g * NH + j] + bg[(g + 1) * NH + j];
    bias_fin[j] = b_Wh[j] + b_We[j] + b_Wg[j] + bh_p[j];
}

// per-row init: Dt, A_big[0] (h=0, x=x_0); block 0 zeroes barrier region
__global__ void k_init(const float* __restrict__ X_seq, float* __restrict__ Dt,
                       __hip_bfloat16* __restrict__ A_big, unsigned* __restrict__ bar) {
    int b = blockIdx.x, tid = threadIdx.x;
    if (b == 0) for (int i = tid; i < BAR_TOT; i += 256) bar[i] = 0;
    if (tid < NT) Dt[tid * NB + b] = X_seq[((size_t)b * NT + tid) * (ND + 1) + ND];
    for (int c = tid; c < KKB; c += 256) {
        float v = 0.f;
        if (c >= 512 && c < 640) v = X_seq[(size_t)b * NT * (ND + 1) + (c - 512)];
        A_big[(size_t)b * KKB + c] = __float2bfloat16(v);
    }
}

// ---------------- global fallback barrier (round-6, proven) ----------------
__device__ __forceinline__ void gbar2(unsigned* __restrict__ gb, int wg, unsigned gen) {
    __syncthreads();
    const int tid = threadIdx.x;
    if (tid == 0) st_rel_sys(&gb[wg * 32], gen);
    if (wg == 0) {
        while (ld_rlx_sys(&gb[tid * 32]) < gen) {}
        (void)ld_acq_sys(&gb[tid * 32]);
        __syncthreads();
        if (tid == 0) st_rel_sys(&gb[256 * 32], gen);
    }
    if (tid == 0) {
        while (ld_rlx_sys(&gb[256 * 32]) < gen) {}
        (void)ld_acq_sys(&gb[256 * 32]);
    }
    __syncthreads();
}

// ---------------- intra-XCD barrier (local mode) ----------------
__device__ __forceinline__ void gbarL(unsigned* __restrict__ bar, unsigned xcd, unsigned rank,
                                      unsigned gen) {
    const int tid = threadIdx.x;
    __syncthreads();                                   // data ack'd into local L2
    if (tid == 0) st_rlx_agt(&bar[BAR_MFL + (xcd * 32 + rank) * 16], gen);
    if (rank == 0) {
        if (tid < 32) { while (ld_rlx_agt(&bar[BAR_MFL + (xcd * 32 + tid) * 16]) < gen) {} }
        __syncthreads();
        if (tid == 0) st_rlx_agt(&bar[BAR_DFL + xcd * 32], gen);
    }
    if (tid == 0) {
        while (ld_rlx_agt(&bar[BAR_DFL + xcd * 32]) < gen) {}
        (void)ld_acq_agt(&bar[BAR_DFL + xcd * 32]);    // inv L1 (CU-wide)
    }
    __syncthreads();
}

// ---------------- persistent LSTM kernel: row-split by physical XCD ----------------

__global__ __launch_bounds__(256, 1) void lstm_coop(
    const float* __restrict__ X_seq, const float* __restrict__ Dt,
    const __hip_bfloat16* __restrict__ WA_shuf, const __hip_bfloat16* __restrict__ WB_shuf,
    const float* __restrict__ bias_s, const float* __restrict__ bias_g,
    const float* __restrict__ Wst,
    __hip_bfloat16* __restrict__ A_big,       // [2][NB][KKB]
    float* __restrict__ c_last, float* __restrict__ s_f32, float* __restrict__ h_last,
    __hip_bfloat16* __restrict__ hist,        // [NMEM][NB][NH]
    unsigned* __restrict__ bar)
{
    const int wg = blockIdx.x;       // 0..255
    const int tid = threadIdx.x;
    const int wv = tid >> 6;         // 0..3
    const int lane = tid & 63;
    const int l15 = lane & 15, lhi = lane >> 4;

    // ---- one-time XCD membership registration ----
    __shared__ unsigned sh_meta[2];
    __shared__ unsigned sh_cnt[8];
    if (tid == 0) {
        unsigned xcc;
        asm volatile("s_getreg_b32 %0, hwreg(HW_REG_XCC_ID)" : "=s"(xcc));
        xcc &= 7u;
        unsigned r = __hip_atomic_fetch_add(&bar[BAR_CNT + xcc], 1u,
                                            __ATOMIC_RELAXED, __HIP_MEMORY_SCOPE_AGENT);
        sh_meta[0] = xcc; sh_meta[1] = r;
    }
    __syncthreads();
    gbar2(bar + BAR_GB, wg, 1u);                 // counts final + visible
    if (tid < 8) sh_cnt[tid] = ld_rlx_sys(&bar[BAR_CNT + tid]);
    __syncthreads();
    bool local_ok = true;
    #pragma unroll
    for (int j = 0; j < 8; ++j) if (sh_cnt[j] != 32u) local_ok = false;

    // local mode: physical XCD grouping; fallback: logical grouping + sys barrier
    const unsigned xcd  = local_ok ? sh_meta[0] : (unsigned)(wg & 7);
    const unsigned rank = local_ok ? sh_meta[1] : (unsigned)(wg >> 3);
    const int row_base  = (int)xcd * 64;         // this group owns rows [row_base, +64)

    const int colj = (int)rank * 16 + l15;       // output column (phase A and B)

    const float ebs  = bias_s[colj];
    const float ewst = Wst[colj];
    float bgc[5];
    #pragma unroll
    for (int g = 0; g < 5; ++g) bgc[g] = bias_g[g * NH + colj];

    const __hip_bfloat16* wa_base = WA_shuf + (size_t)rank * 20 * 512 + lane * 8;
    const __hip_bfloat16* wb_base = WB_shuf + (size_t)rank * 5 * 36 * 512 + lane * 8;

    f32x4 c_reg = {0.f, 0.f, 0.f, 0.f};          // c for rows (wv,lhi,r) x col colj

    for (int t = 0; t < NT; ++t) {
        const int buf = t & 1;
        const __hip_bfloat16* A = A_big + (size_t)buf * NB * KKB;
        __hip_bfloat16* An = A_big + (size_t)(buf ^ 1) * NB * KKB;
        __hip_bfloat16* Aw = A_big + (size_t)buf * NB * KKB;

        // ---- phase A: s = tanh([h|x]@WA + d*Wst + bias_s); 64 rows x 16 cols per WG
        {
            f32x4 acc = {0.f, 0.f, 0.f, 0.f};
            const __hip_bfloat16* arow = A + (size_t)(row_base + wv * 16 + l15) * KKB + lhi * 8;
            #pragma unroll 4
            for (int kk = 0; kk < 20; ++kk) {
                bf16x8 af = *reinterpret_cast<const bf16x8*>(arow + kk * 32);
                bf16x8 bfv = *reinterpret_cast<const bf16x8*>(wa_base + kk * 512);
                acc = __builtin_amdgcn_mfma_f32_16x16x32_bf16(af, bfv, acc, 0, 0, 0);
            }
            #pragma unroll
            for (int r = 0; r < 4; ++r) {
                int row = row_base + wv * 16 + lhi * 4 + r;
                float s = tanhf(acc[r] + ebs + Dt[t * NB + row] * ewst);
                s_f32[row * NH + colj] = s;
                Aw[(size_t)row * KKB + 640 + colj] = __float2bfloat16(s);
            }
        }
        if (local_ok) gbarL(bar, xcd, rank, (unsigned)(2 * t + 1));
        else          gbar2(bar + BAR_GB, wg, (unsigned)(2 * t + 2));

        // ---- phase B: 5 gates; 64 rows x 16 j-cols x 5 gates per WG; fused cell
        {
            f32x4 acc[5] = {};
            const __hip_bfloat16* arow = A + (size_t)(row_base + wv * 16 + l15) * KKB + lhi * 8;
            for (int kk = 0; kk < 36; ++kk) {
                bf16x8 af = *reinterpret_cast<const bf16x8*>(arow + kk * 32);
                #pragma unroll
                for (int g = 0; g < 5; ++g) {
                    bf16x8 bfv = *reinterpret_cast<const bf16x8*>(wb_base + (g * 36 + kk) * 512);
                    acc[g] = __builtin_amdgcn_mfma_f32_16x16x32_bf16(af, bfv, acc[g], 0, 0, 0);
                }
            }
            #pragma unroll
            for (int r = 0; r < 4; ++r) {
                int row = row_base + wv * 16 + lhi * 4 + r;
                float f  = sigm_(acc[0][r] + bgc[0]);
                float i  = sigm_(acc[1][r] + bgc[1]);
                float Tg = sigm_(acc[2][r] + bgc[2]);
                float z  = tanhf(acc[3][r] + bgc[3]);
                float o  = sigm_(acc[4][r] + bgc[4]);
                float sv = s_f32[row * NH + colj];
                float cn = f * c_reg[r] + i * z + Tg * sv;
                c_reg[r] = cn;
                float hn = o * tanhf(cn);
                An[(size_t)row * KKB + colj] = __float2bfloat16(hn);
                if (t >= NT - NMEM)
                    hist[((size_t)(t - (NT - NMEM)) * NB + row) * NH + colj] = __float2bfloat16(hn);
                if (t == NT - 1) {
                    h_last[row * NH + colj] = hn;
                    c_last[row * NH + colj] = cn;
                }
            }
            // stage x_{t+1} for this group's 64 rows: 32 WGs x 256 threads = 8192 elems
            if (t < NT - 1) {
                int idx = (int)rank * 256 + tid;    // 0..8191
                int rr = idx >> 7, d = idx & 127;
                int row = row_base + rr;
                float xv = X_seq[((size_t)row * NT + (t + 1)) * (ND + 1) + d];
                An[(size_t)row * KKB + 512 + d] = __float2bfloat16(xv);
            }
        }
        if (local_ok) gbarL(bar, xcd, rank, (unsigned)(2 * t + 2));
        else          gbar2(bar + BAR_GB, wg, (unsigned)(2 * t + 3));
    }
}

// ---------------- attention + head (unchanged) ----------------

__global__ void k_qa(const float* __restrict__ h_last, const float* __restrict__ c_last,
                     const float* __restrict__ Waq, const float* __restrict__ baq,
                     float* __restrict__ qa) {
    __shared__ float qs[8][1024];
    int b0 = blockIdx.x * 8;
    for (int idx = threadIdx.x; idx < 8 * 1024; idx += 512) {
        int bb = idx >> 10, k = idx & 1023;
        qs[bb][k] = (k < 512) ? h_last[(b0 + bb) * NH + k] : c_last[(b0 + bb) * NH + (k - 512)];
    }
    __syncthreads();
    int j = threadIdx.x;
    float acc[8] = {};
    for (int k = 0; k < 1024; ++k) {
        float w = Waq[(size_t)k * NH + j];
        #pragma unroll
        for (int bb = 0; bb < 8; ++bb) acc[bb] += qs[bb][k] * w;
    }
    float bq = baq[j];
    for (int bb = 0; bb < 8; ++bb) qa[(b0 + bb) * NH + j] = acc[bb] + bq;
}

__global__ void k_scores(const __hip_bfloat16* __restrict__ hist,
                         const __hip_bfloat16* __restrict__ Wah_shuf,
                         const float* __restrict__ qa, const float* __restrict__ bah,
                         const float* __restrict__ vt, float* __restrict__ score_part) {
    int rt = blockIdx.x, jt = blockIdx.y;
    int tid = threadIdx.x, wv = tid >> 6, lane = tid & 63;
    int l15 = lane & 15, lhi = lane >> 4;
    int R0 = rt * 64 + wv * 16;
    f32x4 acc[4] = {};
    const __hip_bfloat16* arow = hist + (size_t)(R0 + l15) * NH + lhi * 8;
    const __hip_bfloat16* bbase = Wah_shuf + lane * 8;
    for (int kk = 0; kk < 16; ++kk) {
        bf16x8 af = *reinterpret_cast<const bf16x8*>(arow + kk * 32);
        #pragma unroll
        for (int f = 0; f < 4; ++f) {
            int nb = jt * 4 + f;
            bf16x8 bfv = *reinterpret_cast<const bf16x8*>(bbase + (size_t)(nb * 16 + kk) * 512);
            acc[f] = __builtin_amdgcn_mfma_f32_16x16x32_bf16(af, bfv, acc[f], 0, 0, 0);
        }
    }
    float part[4] = {};
    #pragma unroll
    for (int r = 0; r < 4; ++r) {
        int R = R0 + lhi * 4 + r;
        int b = R & (NB - 1);
        #pragma unroll
        for (int f = 0; f < 4; ++f) {
            int j = (jt * 4 + f) * 16 + l15;
            float v = acc[f][r] + qa[b * NH + j] + bah[j];
            part[r] += tanhf(v) * vt[j];
        }
    }
    #pragma unroll
    for (int m = 1; m <= 8; m <<= 1)
        #pragma unroll
        for (int r = 0; r < 4; ++r) part[r] += __shfl_xor(part[r], m);
    if (l15 == 0)
        #pragma unroll
        for (int r = 0; r < 4; ++r)
            score_part[(size_t)jt * (NMEM * NB) + R0 + lhi * 4 + r] = part[r];
}

__global__ void k_softmax_e(const float* __restrict__ score_part,
                            const __hip_bfloat16* __restrict__ hist,
                            float* __restrict__ e_buf) {
    int b = blockIdx.x, m = threadIdx.x;  // 64 threads
    float sc = 0.f;
    for (int p = 0; p < 8; ++p) sc += score_part[(size_t)p * (NMEM * NB) + m * NB + b];
    float mx = sc;
    for (int off = 32; off; off >>= 1) mx = fmaxf(mx, __shfl_xor(mx, off));
    float ex = expf(sc - mx);
    float sm = ex;
    for (int off = 32; off; off >>= 1) sm += __shfl_xor(sm, off);
    float alpha = ex / sm;
    __shared__ float al[64];
    al[m] = alpha;
    __syncthreads();
    for (int j0 = 0; j0 < NH; j0 += 64) {
        int j = j0 + m;
        float acc = 0.f;
        for (int mm = 0; mm < 64; ++mm)
            acc += al[mm] * __bfloat162float(hist[((size_t)mm * NB + b) * NH + j]);
        e_buf[b * NH + j] = acc;
    }
}

__global__ void k_final(const float* __restrict__ h_last, const float* __restrict__ e_buf,
                        const float* __restrict__ X_seq, const float* __restrict__ W_h,
                        const float* __restrict__ We, const float* __restrict__ Wg,
                        const float* __restrict__ bias_fin, float* __restrict__ h_fin) {
    __shared__ float hs[8][512], es[8][512], xs[8][128];
    int b0 = blockIdx.x * 8;
    for (int idx = threadIdx.x; idx < 8 * 512; idx += 512) {
        int bb = idx >> 9, k = idx & 511;
        hs[bb][k] = h_last[(b0 + bb) * NH + k];
        es[bb][k] = e_buf[(b0 + bb) * NH + k];
    }
    for (int idx = threadIdx.x; idx < 8 * 128; idx += 512) {
        int bb = idx >> 7, d = idx & 127;
        xs[bb][d] = X_seq[((size_t)(b0 + bb) * NT + (NT - 1)) * (ND + 1) + d];
    }
    __syncthreads();
    int j = threadIdx.x;
    float acc[8];
    float bfv = bias_fin[j];
    #pragma unroll
    for (int bb = 0; bb < 8; ++bb) acc[bb] = bfv;
    for (int k = 0; k < 512; ++k) {
        float w = W_h[(size_t)k * NH + j];
        #pragma unroll
        for (int bb = 0; bb < 8; ++bb) acc[bb] += hs[bb][k] * w;
    }
    for (int k = 0; k < 512; ++k) {
        float w = We[(size_t)k * NH + j];
        #pragma unroll
        for (int bb = 0; bb < 8; ++bb) acc[bb] += es[bb][k] * w;
    }
    for (int d = 0; d < 128; ++d) {
        float w = Wg[(size_t)d * NH + j];
        #pragma unroll
        for (int bb = 0; bb < 8; ++bb) acc[bb] += xs[bb][d] * w;
    }
    for (int bb = 0; bb < 8; ++bb) h_fin[(b0 + bb) * NH + j] = tanhf(acc[bb]);
}

__global__ void k_out(const float* __restrict__ h_fin, const float* __restrict__ Wc,
                      const float* __restrict__ bc, float* __restrict__ out) {
    int b = blockIdx.x, tid = threadIdx.x;  // 256 threads
    float p = 0.f;
    for (int j = tid; j < NH; j += 256) p += h_fin[b * NH + j] * Wc[j];
    for (int off = 32; off; off >>= 1) p += __shfl_xor(p, off);
    __shared__ float red[4];
    if ((tid & 63) == 0) red[tid >> 6] = p;
    __syncthreads();
    if (tid == 0) out[b] = 1.f / (1.f + expf(-(red[0] + red[1] + red[2] + red[3] + bc[0])));
}

// ---------------- launch ----------------

extern "C" void kernel_launch(void* const* d_in, const int* in_sizes, int n_in,
                              void* d_out, int out_size, void* d_ws, size_t ws_size,
                              hipStream_t stream) {
    const float* X_seq  = (const float*)d_in[0];
    const float* Wh     = (const float*)d_in[1];
    const float* bh_lin = (const float*)d_in[2];
    const float* Wx     = (const float*)d_in[3];
    const float* bx_lin = (const float*)d_in[4];
    const float* Wst    = (const float*)d_in[5];
    const float* bst    = (const float*)d_in[6];
    const float* Ws     = (const float*)d_in[7];
    const float* bs_lin = (const float*)d_in[8];
    const float* bg     = (const float*)d_in[9];
    const float* Waq    = (const float*)d_in[10];
    const float* baq    = (const float*)d_in[11];
    const float* Wah    = (const float*)d_in[12];
    const float* bah    = (const float*)d_in[13];
    const float* vt     = (const float*)d_in[14];
    const float* W_h    = (const float*)d_in[15];
    const float* b_Wh   = (const float*)d_in[16];
    const float* We     = (const float*)d_in[17];
    const float* b_We   = (const float*)d_in[18];
    const float* Wg     = (const float*)d_in[19];
    const float* b_Wg   = (const float*)d_in[20];
    const float* bh_p   = (const float*)d_in[21];
    const float* Wc     = (const float*)d_in[22];
    const float* bc     = (const float*)d_in[23];
    float* out = (float*)d_out;

    char* ws = (char*)d_ws;
    size_t off = 0;
    auto alloc = [&](size_t bytes) -> char* {
        char* p = ws + off;
        off = (off + bytes + 255) & ~(size_t)255;
        return p;
    };
    __hip_bfloat16* WA_shuf  = (__hip_bfloat16*)alloc((size_t)KKA * NH * 2);
    __hip_bfloat16* WB_shuf  = (__hip_bfloat16*)alloc((size_t)KKB * 5 * NH * 2);
    __hip_bfloat16* Wah_shuf = (__hip_bfloat16*)alloc((size_t)NH * NH * 2);
    float* bias_s   = (float*)alloc(NH * 4);
    float* bias_g   = (float*)alloc(5 * NH * 4);
    float* bias_fin = (float*)alloc(NH * 4);
    float* Dt       = (float*)alloc((size_t)NT * NB * 4);
    __hip_bfloat16* A_big = (__hip_bfloat16*)alloc((size_t)2 * NB * KKB * 2);
    float* c_last   = (float*)alloc((size_t)NB * NH * 4);
    float* s_f32    = (float*)alloc((size_t)NB * NH * 4);
    float* h_last   = (float*)alloc((size_t)NB * NH * 4);
    __hip_bfloat16* hist = (__hip_bfloat16*)alloc((size_t)NMEM * NB * NH * 2);
    float* qa       = (float*)alloc((size_t)NB * NH * 4);
    float* score_part = (float*)alloc((size_t)8 * NMEM * NB * 4);
    float* e_buf    = (float*)alloc((size_t)NB * NH * 4);
    float* h_fin    = (float*)alloc((size_t)NB * NH * 4);
    unsigned* bar   = (unsigned*)alloc((size_t)BAR_TOT * 4 + 4096);

    // prep
    hipLaunchKernelGGL(k_shufA, dim3(32 * 20), dim3(64), 0, stream, Wh, Wx, WA_shuf);
    hipLaunchKernelGGL(k_shufB, dim3(32 * 5 * 36), dim3(64), 0, stream, Wh, Wx, Ws, WB_shuf);
    hipLaunchKernelGGL(k_shufW, dim3(32 * 16), dim3(64), 0, stream, Wah, Wah_shuf);
    hipLaunchKernelGGL(k_biases, dim3(1), dim3(512), 0, stream,
                       bh_lin, bx_lin, bst, bs_lin, bg, b_Wh, b_We, b_Wg, bh_p,
                       bias_s, bias_g, bias_fin);
    hipLaunchKernelGGL(k_init, dim3(NB), dim3(256), 0, stream, X_seq, Dt, A_big, bar);

    // persistent recurrent kernel (cooperative launch for co-residency guarantee)
    {
        void* args[] = {(void*)&X_seq, (void*)&Dt, (void*)&WA_shuf, (void*)&WB_shuf,
                        (void*)&bias_s, (void*)&bias_g, (void*)&Wst, (void*)&A_big,
                        (void*)&c_last, (void*)&s_f32, (void*)&h_last, (void*)&hist,
                        (void*)&bar};
        hipLaunchCooperativeKernel((void*)lstm_coop, dim3(256), dim3(256), args, 0, stream);
    }

    // attention + head
    hipLaunchKernelGGL(k_qa, dim3(64), dim3(512), 0, stream, h_last, c_last, Waq, baq, qa);
    hipLaunchKernelGGL(k_scores, dim3(512, 8), dim3(256), 0, stream,
                       hist, Wah_shuf, qa, bah, vt, score_part);
    hipLaunchKernelGGL(k_softmax_e, dim3(NB), dim3(64), 0, stream, score_part, hist, e_buf);
    hipLaunchKernelGGL(k_final, dim3(64), dim3(512), 0, stream,
                       h_last, e_buf, X_seq, W_h, We, Wg, bias_fin, h_fin);
    hipLaunchKernelGGL(k_out, dim3(NB), dim3(256), 0, stream, h_fin, Wc, bc, out);
}

// Round 15
// 3861.774 us; speedup vs baseline: 1.5353x; 1.0000x over previous
//
#include <hip/hip_runtime.h>
#include <hip/hip_bf16.h>

typedef __bf16 bf16x8 __attribute__((ext_vector_type(8)));
typedef float f32x4 __attribute__((ext_vector_type(4)));

constexpr int NB   = 512;   // batch
constexpr int NT   = 128;   // timesteps
constexpr int ND   = 128;   // input dim
constexpr int NH   = 512;   // hidden
constexpr int NMEM = 64;    // attention memory
constexpr int KKA  = 640;   // h(512)+x(128)
constexpr int KKB  = 1152;  // h(512)+x(128)+s(512)

// barrier region layout (u32 indices)
constexpr int BAR_CNT = 0;        // [8] per-XCD member counts
constexpr int BAR_GB  = 64;       // [257] stride 32: global fallback/setup barrier flags
constexpr int BAR_MFL = 8448;     // [8][32] stride 16: per-XCD member flags
constexpr int BAR_DFL = 12800;    // [8] stride 32: per-XCD done flags
constexpr int BAR_TOT = 16384;

__device__ __forceinline__ float sigm_(float x) { return 1.f / (1.f + expf(-x)); }

// ---- atomic helpers ----
__device__ __forceinline__ unsigned ld_rlx_sys(const unsigned* p) {
    return __hip_atomic_load(p, __ATOMIC_RELAXED, __HIP_MEMORY_SCOPE_SYSTEM);
}
__device__ __forceinline__ unsigned ld_acq_sys(const unsigned* p) {
    return __hip_atomic_load(p, __ATOMIC_ACQUIRE, __HIP_MEMORY_SCOPE_SYSTEM);
}
__device__ __forceinline__ void st_rel_sys(unsigned* p, unsigned v) {
    __hip_atomic_store(p, v, __ATOMIC_RELEASE, __HIP_MEMORY_SCOPE_SYSTEM);
}
__device__ __forceinline__ unsigned ld_rlx_agt(const unsigned* p) {
    return __hip_atomic_load(p, __ATOMIC_RELAXED, __HIP_MEMORY_SCOPE_AGENT);
}
__device__ __forceinline__ unsigned ld_acq_agt(const unsigned* p) {
    return __hip_atomic_load(p, __ATOMIC_ACQUIRE, __HIP_MEMORY_SCOPE_AGENT);
}
__device__ __forceinline__ void st_rlx_agt(unsigned* p, unsigned v) {
    __hip_atomic_store(p, v, __ATOMIC_RELAXED, __HIP_MEMORY_SCOPE_AGENT);
}

// ---------------- prep kernels ----------------

__global__ void k_shufA(const float* __restrict__ Wh, const float* __restrict__ Wx,
                        __hip_bfloat16* __restrict__ WA_shuf) {
    int nb = blockIdx.x / 20, kk = blockIdx.x % 20;
    int lane = threadIdx.x;
    int n = nb * 16 + (lane & 15);
    int kbase = kk * 32 + (lane >> 4) * 8;
    size_t o = ((size_t)blockIdx.x * 64 + lane) * 8;
    for (int e = 0; e < 8; ++e) {
        int k = kbase + e;
        float v = (k < 512) ? Wh[(size_t)k * NH + n]
                            : Wx[(size_t)(k - 512) * NH + n];
        WA_shuf[o + e] = __float2bfloat16(v);
    }
}

__global__ void k_shufB(const float* __restrict__ Wh, const float* __restrict__ Wx,
                        const float* __restrict__ Ws, __hip_bfloat16* __restrict__ WB_shuf) {
    int idx = blockIdx.x;                 // jb*180 + g*36 + kk
    int kk = idx % 36, g = (idx / 36) % 5, jb = idx / 180;
    int lane = threadIdx.x;
    int j = jb * 16 + (lane & 15);
    int kbase = kk * 32 + (lane >> 4) * 8;
    size_t o = ((size_t)idx * 64 + lane) * 8;
    for (int e = 0; e < 8; ++e) {
        int k = kbase + e;
        float v;
        if (k < 512)      v = Wh[(size_t)(g + 1) * NH * NH + (size_t)k * NH + j];
        else if (k < 640) v = Wx[(size_t)(g + 1) * ND * NH + (size_t)(k - 512) * NH + j];
        else              v = Ws[(size_t)g * NH * NH + (size_t)(k - 640) * NH + j];
        WB_shuf[o + e] = __float2bfloat16(v);
    }
}

__global__ void k_shufW(const float* __restrict__ Wah, __hip_bfloat16* __restrict__ Wah_shuf) {
    int nb = blockIdx.x / 16, kk = blockIdx.x % 16;
    int lane = threadIdx.x;
    int j = nb * 16 + (lane & 15);
    int kbase = kk * 32 + (lane >> 4) * 8;
    size_t o = ((size_t)blockIdx.x * 64 + lane) * 8;
    for (int e = 0; e < 8; ++e)
        Wah_shuf[o + e] = __float2bfloat16(Wah[(size_t)(kbase + e) * NH + j]);
}

__global__ void k_biases(const float* bh_lin, const float* bx_lin, const float* bst,
                         const float* bs_lin, const float* bg,
                         const float* b_Wh, const float* b_We, const float* b_Wg, const float* bh_p,
                         float* bias_s, float* bias_g, float* bias_fin) {
    int j = threadIdx.x;
    bias_s[j] = bh_lin[j] + bx_lin[j] + bst[j] + bg[j];
    for (int g = 0; g < 5; ++g)
        bias_g[g * NH + j] = bh_lin[(g + 1) * NH + j] + bx_lin[(g + 1) * NH + j] +
                             bs_lin[g * NH + j] + bg[(g + 1) * NH + j];
    bias_fin[j] = b_Wh[j] + b_We[j] + b_Wg[j] + bh_p[j];
}

// per-row init: Dt, A_big[0] (h=0, x=x_0); block 0 zeroes barrier region
__global__ void k_init(const float* __restrict__ X_seq, float* __restrict__ Dt,
                       __hip_bfloat16* __restrict__ A_big, unsigned* __restrict__ bar) {
    int b = blockIdx.x, tid = threadIdx.x;
    if (b == 0) for (int i = tid; i < BAR_TOT; i += 256) bar[i] = 0;
    if (tid < NT) Dt[tid * NB + b] = X_seq[((size_t)b * NT + tid) * (ND + 1) + ND];
    for (int c = tid; c < KKB; c += 256) {
        float v = 0.f;
        if (c >= 512 && c < 640) v = X_seq[(size_t)b * NT * (ND + 1) + (c - 512)];
        A_big[(size_t)b * KKB + c] = __float2bfloat16(v);
    }
}

// ---------------- global fallback barrier (round-6, proven) ----------------
__device__ __forceinline__ void gbar2(unsigned* __restrict__ gb, int wg, unsigned gen) {
    __syncthreads();
    const int tid = threadIdx.x;
    if (tid == 0) st_rel_sys(&gb[wg * 32], gen);
    if (wg == 0) {
        while (ld_rlx_sys(&gb[tid * 32]) < gen) {}
        (void)ld_acq_sys(&gb[tid * 32]);
        __syncthreads();
        if (tid == 0) st_rel_sys(&gb[256 * 32], gen);
    }
    if (tid == 0) {
        while (ld_rlx_sys(&gb[256 * 32]) < gen) {}
        (void)ld_acq_sys(&gb[256 * 32]);
    }
    __syncthreads();
}

// ---------------- intra-XCD barrier (local mode) ----------------
__device__ __forceinline__ void gbarL(unsigned* __restrict__ bar, unsigned xcd, unsigned rank,
                                      unsigned gen) {
    const int tid = threadIdx.x;
    __syncthreads();                                   // data ack'd into local L2
    if (tid == 0) st_rlx_agt(&bar[BAR_MFL + (xcd * 32 + rank) * 16], gen);
    if (rank == 0) {
        if (tid < 32) { while (ld_rlx_agt(&bar[BAR_MFL + (xcd * 32 + tid) * 16]) < gen) {} }
        __syncthreads();
        if (tid == 0) st_rlx_agt(&bar[BAR_DFL + xcd * 32], gen);
    }
    if (tid == 0) {
        while (ld_rlx_agt(&bar[BAR_DFL + xcd * 32]) < gen) {}
        (void)ld_acq_agt(&bar[BAR_DFL + xcd * 32]);    // inv L1 (CU-wide)
    }
    __syncthreads();
}

// ---------------- persistent LSTM kernel: row-split by physical XCD ----------------

__global__ __launch_bounds__(256, 1) void lstm_coop(
    const float* __restrict__ X_seq, const float* __restrict__ Dt,
    const __hip_bfloat16* __restrict__ WA_shuf, const __hip_bfloat16* __restrict__ WB_shuf,
    const float* __restrict__ bias_s, const float* __restrict__ bias_g,
    const float* __restrict__ Wst,
    __hip_bfloat16* __restrict__ A_big,       // [2][NB][KKB]
    float* __restrict__ c_last, float* __restrict__ s_f32, float* __restrict__ h_last,
    __hip_bfloat16* __restrict__ hist,        // [NMEM][NB][NH]
    unsigned* __restrict__ bar)
{
    const int wg = blockIdx.x;       // 0..255
    const int tid = threadIdx.x;
    const int wv = tid >> 6;         // 0..3
    const int lane = tid & 63;
    const int l15 = lane & 15, lhi = lane >> 4;

    // ---- one-time XCD membership registration ----
    __shared__ unsigned sh_meta[2];
    __shared__ unsigned sh_cnt[8];
    if (tid == 0) {
        unsigned xcc;
        asm volatile("s_getreg_b32 %0, hwreg(HW_REG_XCC_ID)" : "=s"(xcc));
        xcc &= 7u;
        unsigned r = __hip_atomic_fetch_add(&bar[BAR_CNT + xcc], 1u,
                                            __ATOMIC_RELAXED, __HIP_MEMORY_SCOPE_AGENT);
        sh_meta[0] = xcc; sh_meta[1] = r;
    }
    __syncthreads();
    gbar2(bar + BAR_GB, wg, 1u);                 // counts final + visible
    if (tid < 8) sh_cnt[tid] = ld_rlx_sys(&bar[BAR_CNT + tid]);
    __syncthreads();
    bool local_ok = true;
    #pragma unroll
    for (int j = 0; j < 8; ++j) if (sh_cnt[j] != 32u) local_ok = false;

    // local mode: physical XCD grouping; fallback: logical grouping + sys barrier
    const unsigned xcd  = local_ok ? sh_meta[0] : (unsigned)(wg & 7);
    const unsigned rank = local_ok ? sh_meta[1] : (unsigned)(wg >> 3);
    const int row_base  = (int)xcd * 64;         // this group owns rows [row_base, +64)

    const int colj = (int)rank * 16 + l15;       // output column (phase A and B)

    const float ebs  = bias_s[colj];
    const float ewst = Wst[colj];
    float bgc[5];
    #pragma unroll
    for (int g = 0; g < 5; ++g) bgc[g] = bias_g[g * NH + colj];

    const __hip_bfloat16* wa_base = WA_shuf + (size_t)rank * 20 * 512 + lane * 8;
    const __hip_bfloat16* wb_base = WB_shuf + (size_t)rank * 5 * 36 * 512 + lane * 8;

    f32x4 c_reg = {0.f, 0.f, 0.f, 0.f};          // c for rows (wv,lhi,r) x col colj

    for (int t = 0; t < NT; ++t) {
        const int buf = t & 1;
        const __hip_bfloat16* A = A_big + (size_t)buf * NB * KKB;
        __hip_bfloat16* An = A_big + (size_t)(buf ^ 1) * NB * KKB;
        __hip_bfloat16* Aw = A_big + (size_t)buf * NB * KKB;

        // ---- phase A: s = tanh([h|x]@WA + d*Wst + bias_s); 64 rows x 16 cols per WG
        {
            f32x4 acc = {0.f, 0.f, 0.f, 0.f};
            const __hip_bfloat16* arow = A + (size_t)(row_base + wv * 16 + l15) * KKB + lhi * 8;
            #pragma unroll 4
            for (int kk = 0; kk < 20; ++kk) {
                bf16x8 af = *reinterpret_cast<const bf16x8*>(arow + kk * 32);
                bf16x8 bfv = *reinterpret_cast<const bf16x8*>(wa_base + kk * 512);
                acc = __builtin_amdgcn_mfma_f32_16x16x32_bf16(af, bfv, acc, 0, 0, 0);
            }
            #pragma unroll
            for (int r = 0; r < 4; ++r) {
                int row = row_base + wv * 16 + lhi * 4 + r;
                float s = tanhf(acc[r] + ebs + Dt[t * NB + row] * ewst);
                s_f32[row * NH + colj] = s;
                Aw[(size_t)row * KKB + 640 + colj] = __float2bfloat16(s);
            }
        }
        if (local_ok) gbarL(bar, xcd, rank, (unsigned)(2 * t + 1));
        else          gbar2(bar + BAR_GB, wg, (unsigned)(2 * t + 2));

        // ---- phase B: 5 gates; 64 rows x 16 j-cols x 5 gates per WG; fused cell
        {
            f32x4 acc[5] = {};
            const __hip_bfloat16* arow = A + (size_t)(row_base + wv * 16 + l15) * KKB + lhi * 8;
            for (int kk = 0; kk < 36; ++kk) {
                bf16x8 af = *reinterpret_cast<const bf16x8*>(arow + kk * 32);
                #pragma unroll
                for (int g = 0; g < 5; ++g) {
                    bf16x8 bfv = *reinterpret_cast<const bf16x8*>(wb_base + (g * 36 + kk) * 512);
                    acc[g] = __builtin_amdgcn_mfma_f32_16x16x32_bf16(af, bfv, acc[g], 0, 0, 0);
                }
            }
            #pragma unroll
            for (int r = 0; r < 4; ++r) {
                int row = row_base + wv * 16 + lhi * 4 + r;
                float f  = sigm_(acc[0][r] + bgc[0]);
                float i  = sigm_(acc[1][r] + bgc[1]);
                float Tg = sigm_(acc[2][r] + bgc[2]);
                float z  = tanhf(acc[3][r] + bgc[3]);
                float o  = sigm_(acc[4][r] + bgc[4]);
                float sv = s_f32[row * NH + colj];
                float cn = f * c_reg[r] + i * z + Tg * sv;
                c_reg[r] = cn;
                float hn = o * tanhf(cn);
                An[(size_t)row * KKB + colj] = __float2bfloat16(hn);
                if (t >= NT - NMEM)
                    hist[((size_t)(t - (NT - NMEM)) * NB + row) * NH + colj] = __float2bfloat16(hn);
                if (t == NT - 1) {
                    h_last[row * NH + colj] = hn;
                    c_last[row * NH + colj] = cn;
                }
            }
            // stage x_{t+1} for this group's 64 rows: 32 WGs x 256 threads = 8192 elems
            if (t < NT - 1) {
                int idx = (int)rank * 256 + tid;    // 0..8191
                int rr = idx >> 7, d = idx & 127;
                int row = row_base + rr;
                float xv = X_seq[((size_t)row * NT + (t + 1)) * (ND + 1) + d];
                An[(size_t)row * KKB + 512 + d] = __float2bfloat16(xv);
            }
        }
        if (local_ok) gbarL(bar, xcd, rank, (unsigned)(2 * t + 2));
        else          gbar2(bar + BAR_GB, wg, (unsigned)(2 * t + 3));
    }
}

// ---------------- attention + head (unchanged) ----------------

__global__ void k_qa(const float* __restrict__ h_last, const float* __restrict__ c_last,
                     const float* __restrict__ Waq, const float* __restrict__ baq,
                     float* __restrict__ qa) {
    __shared__ float qs[8][1024];
    int b0 = blockIdx.x * 8;
    for (int idx = threadIdx.x; idx < 8 * 1024; idx += 512) {
        int bb = idx >> 10, k = idx & 1023;
        qs[bb][k] = (k < 512) ? h_last[(b0 + bb) * NH + k] : c_last[(b0 + bb) * NH + (k - 512)];
    }
    __syncthreads();
    int j = threadIdx.x;
    float acc[8] = {};
    for (int k = 0; k < 1024; ++k) {
        float w = Waq[(size_t)k * NH + j];
        #pragma unroll
        for (int bb = 0; bb < 8; ++bb) acc[bb] += qs[bb][k] * w;
    }
    float bq = baq[j];
    for (int bb = 0; bb < 8; ++bb) qa[(b0 + bb) * NH + j] = acc[bb] + bq;
}

__global__ void k_scores(const __hip_bfloat16* __restrict__ hist,
                         const __hip_bfloat16* __restrict__ Wah_shuf,
                         const float* __restrict__ qa, const float* __restrict__ bah,
                         const float* __restrict__ vt, float* __restrict__ score_part) {
    int rt = blockIdx.x, jt = blockIdx.y;
    int tid = threadIdx.x, wv = tid >> 6, lane = tid & 63;
    int l15 = lane & 15, lhi = lane >> 4;
    int R0 = rt * 64 + wv * 16;
    f32x4 acc[4] = {};
    const __hip_bfloat16* arow = hist + (size_t)(R0 + l15) * NH + lhi * 8;
    const __hip_bfloat16* bbase = Wah_shuf + lane * 8;
    for (int kk = 0; kk < 16; ++kk) {
        bf16x8 af = *reinterpret_cast<const bf16x8*>(arow + kk * 32);
        #pragma unroll
        for (int f = 0; f < 4; ++f) {
            int nb = jt * 4 + f;
            bf16x8 bfv = *reinterpret_cast<const bf16x8*>(bbase + (size_t)(nb * 16 + kk) * 512);
            acc[f] = __builtin_amdgcn_mfma_f32_16x16x32_bf16(af, bfv, acc[f], 0, 0, 0);
        }
    }
    float part[4] = {};
    #pragma unroll
    for (int r = 0; r < 4; ++r) {
        int R = R0 + lhi * 4 + r;
        int b = R & (NB - 1);
        #pragma unroll
        for (int f = 0; f < 4; ++f) {
            int j = (jt * 4 + f) * 16 + l15;
            float v = acc[f][r] + qa[b * NH + j] + bah[j];
            part[r] += tanhf(v) * vt[j];
        }
    }
    #pragma unroll
    for (int m = 1; m <= 8; m <<= 1)
        #pragma unroll
        for (int r = 0; r < 4; ++r) part[r] += __shfl_xor(part[r], m);
    if (l15 == 0)
        #pragma unroll
        for (int r = 0; r < 4; ++r)
            score_part[(size_t)jt * (NMEM * NB) + R0 + lhi * 4 + r] = part[r];
}

__global__ void k_softmax_e(const float* __restrict__ score_part,
                            const __hip_bfloat16* __restrict__ hist,
                            float* __restrict__ e_buf) {
    int b = blockIdx.x, m = threadIdx.x;  // 64 threads
    float sc = 0.f;
    for (int p = 0; p < 8; ++p) sc += score_part[(size_t)p * (NMEM * NB) + m * NB + b];
    float mx = sc;
    for (int off = 32; off; off >>= 1) mx = fmaxf(mx, __shfl_xor(mx, off));
    float ex = expf(sc - mx);
    float sm = ex;
    for (int off = 32; off; off >>= 1) sm += __shfl_xor(sm, off);
    float alpha = ex / sm;
    __shared__ float al[64];
    al[m] = alpha;
    __syncthreads();
    for (int j0 = 0; j0 < NH; j0 += 64) {
        int j = j0 + m;
        float acc = 0.f;
        for (int mm = 0; mm < 64; ++mm)
            acc += al[mm] * __bfloat162float(hist[((size_t)mm * NB + b) * NH + j]);
        e_buf[b * NH + j] = acc;
    }
}

__global__ void k_final(const float* __restrict__ h_last, const float* __restrict__ e_buf,
                        const float* __restrict__ X_seq, const float* __restrict__ W_h,
                        const float* __restrict__ We, const float* __restrict__ Wg,
                        const float* __restrict__ bias_fin, float* __restrict__ h_fin) {
    __shared__ float hs[8][512], es[8][512], xs[8][128];
    int b0 = blockIdx.x * 8;
    for (int idx = threadIdx.x; idx < 8 * 512; idx += 512) {
        int bb = idx >> 9, k = idx & 511;
        hs[bb][k] = h_last[(b0 + bb) * NH + k];
        es[bb][k] = e_buf[(b0 + bb) * NH + k];
    }
    for (int idx = threadIdx.x; idx < 8 * 128; idx += 512) {
        int bb = idx >> 7, d = idx & 127;
        xs[bb][d] = X_seq[((size_t)(b0 + bb) * NT + (NT - 1)) * (ND + 1) + d];
    }
    __syncthreads();
    int j = threadIdx.x;
    float acc[8];
    float bfv = bias_fin[j];
    #pragma unroll
    for (int bb = 0; bb < 8; ++bb) acc[bb] = bfv;
    for (int k = 0; k < 512; ++k) {
        float w = W_h[(size_t)k * NH + j];
        #pragma unroll
        for (int bb = 0; bb < 8; ++bb) acc[bb] += hs[bb][k] * w;
    }
    for (int k = 0; k < 512; ++k) {
        float w = We[(size_t)k * NH + j];
        #pragma unroll
        for (int bb = 0; bb < 8; ++bb) acc[bb] += es[bb][k] * w;
    }
    for (int d = 0; d < 128; ++d) {
        float w = Wg[(size_t)d * NH + j];
        #pragma unroll
        for (int bb = 0; bb < 8; ++bb) acc[bb] += xs[bb][d] * w;
    }
    for (int bb = 0; bb < 8; ++bb) h_fin[(b0 + bb) * NH + j] = tanhf(acc[bb]);
}

__global__ void k_out(const float* __restrict__ h_fin, const float* __restrict__ Wc,
                      const float* __restrict__ bc, float* __restrict__ out) {
    int b = blockIdx.x, tid = threadIdx.x;  // 256 threads
    float p = 0.f;
    for (int j = tid; j < NH; j += 256) p += h_fin[b * NH + j] * Wc[j];
    for (int off = 32; off; off >>= 1) p += __shfl_xor(p, off);
    __shared__ float red[4];
    if ((tid & 63) == 0) red[tid >> 6] = p;
    __syncthreads();
    if (tid == 0) out[b] = 1.f / (1.f + expf(-(red[0] + red[1] + red[2] + red[3] + bc[0])));
}

// ---------------- launch ----------------

extern "C" void kernel_launch(void* const* d_in, const int* in_sizes, int n_in,
                              void* d_out, int out_size, void* d_ws, size_t ws_size,
                              hipStream_t stream) {
    const float* X_seq  = (const float*)d_in[0];
    const float* Wh     = (const float*)d_in[1];
    const float* bh_lin = (const float*)d_in[2];
    const float* Wx     = (const float*)d_in[3];
    const float* bx_lin = (const float*)d_in[4];
    const float* Wst    = (const float*)d_in[5];
    const float* bst    = (const float*)d_in[6];
    const float* Ws     = (const float*)d_in[7];
    const float* bs_lin = (const float*)d_in[8];
    const float* bg     = (const float*)d_in[9];
    const float* Waq    = (const float*)d_in[10];
    const float* baq    = (const float*)d_in[11];
    const float* Wah    = (const float*)d_in[12];
    const float* bah    = (const float*)d_in[13];
    const float* vt     = (const float*)d_in[14];
    const float* W_h    = (const float*)d_in[15];
    const float* b_Wh   = (const float*)d_in[16];
    const float* We     = (const float*)d_in[17];
    const float* b_We   = (const float*)d_in[18];
    const float* Wg     = (const float*)d_in[19];
    const float* b_Wg   = (const float*)d_in[20];
    const float* bh_p   = (const float*)d_in[21];
    const float* Wc     = (const float*)d_in[22];
    const float* bc     = (const float*)d_in[23];
    float* out = (float*)d_out;

    char* ws = (char*)d_ws;
    size_t off = 0;
    auto alloc = [&](size_t bytes) -> char* {
        char* p = ws + off;
        off = (off + bytes + 255) & ~(size_t)255;
        return p;
    };
    __hip_bfloat16* WA_shuf  = (__hip_bfloat16*)alloc((size_t)KKA * NH * 2);
    __hip_bfloat16* WB_shuf  = (__hip_bfloat16*)alloc((size_t)KKB * 5 * NH * 2);
    __hip_bfloat16* Wah_shuf = (__hip_bfloat16*)alloc((size_t)NH * NH * 2);
    float* bias_s   = (float*)alloc(NH * 4);
    float* bias_g   = (float*)alloc(5 * NH * 4);
    float* bias_fin = (float*)alloc(NH * 4);
    float* Dt       = (float*)alloc((size_t)NT * NB * 4);
    __hip_bfloat16* A_big = (__hip_bfloat16*)alloc((size_t)2 * NB * KKB * 2);
    float* c_last   = (float*)alloc((size_t)NB * NH * 4);
    float* s_f32    = (float*)alloc((size_t)NB * NH * 4);
    float* h_last   = (float*)alloc((size_t)NB * NH * 4);
    __hip_bfloat16* hist = (__hip_bfloat16*)alloc((size_t)NMEM * NB * NH * 2);
    float* qa       = (float*)alloc((size_t)NB * NH * 4);
    float* score_part = (float*)alloc((size_t)8 * NMEM * NB * 4);
    float* e_buf    = (float*)alloc((size_t)NB * NH * 4);
    float* h_fin    = (float*)alloc((size_t)NB * NH * 4);
    unsigned* bar   = (unsigned*)alloc((size_t)BAR_TOT * 4 + 4096);

    // prep
    hipLaunchKernelGGL(k_shufA, dim3(32 * 20), dim3(64), 0, stream, Wh, Wx, WA_shuf);
    hipLaunchKernelGGL(k_shufB, dim3(32 * 5 * 36), dim3(64), 0, stream, Wh, Wx, Ws, WB_shuf);
    hipLaunchKernelGGL(k_shufW, dim3(32 * 16), dim3(64), 0, stream, Wah, Wah_shuf);
    hipLaunchKernelGGL(k_biases, dim3(1), dim3(512), 0, stream,
                       bh_lin, bx_lin, bst, bs_lin, bg, b_Wh, b_We, b_Wg, bh_p,
                       bias_s, bias_g, bias_fin);
    hipLaunchKernelGGL(k_init, dim3(NB), dim3(256), 0, stream, X_seq, Dt, A_big, bar);

    // persistent recurrent kernel (cooperative launch for co-residency guarantee)
    {
        void* args[] = {(void*)&X_seq, (void*)&Dt, (void*)&WA_shuf, (void*)&WB_shuf,
                        (void*)&bias_s, (void*)&bias_g, (void*)&Wst, (void*)&A_big,
                        (void*)&c_last, (void*)&s_f32, (void*)&h_last, (void*)&hist,
                        (void*)&bar};
        hipLaunchCooperativeKernel((void*)lstm_coop, dim3(256), dim3(256), args, 0, stream);
    }

    // attention + head
    hipLaunchKernelGGL(k_qa, dim3(64), dim3(512), 0, stream, h_last, c_last, Waq, baq, qa);
    hipLaunchKernelGGL(k_scores, dim3(512, 8), dim3(256), 0, stream,
                       hist, Wah_shuf, qa, bah, vt, score_part);
    hipLaunchKernelGGL(k_softmax_e, dim3(NB), dim3(64), 0, stream, score_part, hist, e_buf);
    hipLaunchKernelGGL(k_final, dim3(64), dim3(512), 0, stream,
                       h_last, e_buf, X_seq, W_h, We, Wg, bias_fin, h_fin);
    hipLaunchKernelGGL(k_out, dim3(NB), dim3(256), 0, stream, h_fin, Wc, bc, out);
}

// Round 16
// 3844.101 us; speedup vs baseline: 1.5424x; 1.0046x over previous
//
#include <hip/hip_runtime.h>
#include <hip/hip_bf16.h>

typedef __bf16 bf16x8 __attribute__((ext_vector_type(8)));
typedef float f32x4 __attribute__((ext_vector_type(4)));

constexpr int NB   = 512;   // batch
constexpr int NT   = 128;   // timesteps
constexpr int ND   = 128;   // input dim
constexpr int NH   = 512;   // hidden
constexpr int NMEM = 64;    // attention memory
constexpr int KKA  = 640;   // h(512)+x(128)
constexpr int KKB  = 1152;  // h(512)+x(128)+s(512)

// barrier region layout (u32 indices)
constexpr int BAR_CNT = 0;        // [8] per-XCD member counts
constexpr int BAR_GB  = 64;       // [257] stride 32: global fallback/setup barrier flags
constexpr int BAR_MFL = 8448;     // [8][32] stride 16: per-XCD member flags
constexpr int BAR_DFL = 12800;    // [8] stride 32: per-XCD done flags
constexpr int BAR_TOT = 16384;

__device__ __forceinline__ float sigm_(float x) { return 1.f / (1.f + expf(-x)); }

// ---- atomic helpers ----
__device__ __forceinline__ unsigned ld_rlx_sys(const unsigned* p) {
    return __hip_atomic_load(p, __ATOMIC_RELAXED, __HIP_MEMORY_SCOPE_SYSTEM);
}
__device__ __forceinline__ unsigned ld_acq_sys(const unsigned* p) {
    return __hip_atomic_load(p, __ATOMIC_ACQUIRE, __HIP_MEMORY_SCOPE_SYSTEM);
}
__device__ __forceinline__ void st_rel_sys(unsigned* p, unsigned v) {
    __hip_atomic_store(p, v, __ATOMIC_RELEASE, __HIP_MEMORY_SCOPE_SYSTEM);
}
__device__ __forceinline__ unsigned ld_rlx_agt(const unsigned* p) {
    return __hip_atomic_load(p, __ATOMIC_RELAXED, __HIP_MEMORY_SCOPE_AGENT);
}
__device__ __forceinline__ unsigned ld_acq_agt(const unsigned* p) {
    return __hip_atomic_load(p, __ATOMIC_ACQUIRE, __HIP_MEMORY_SCOPE_AGENT);
}
__device__ __forceinline__ void st_rlx_agt(unsigned* p, unsigned v) {
    __hip_atomic_store(p, v, __ATOMIC_RELAXED, __HIP_MEMORY_SCOPE_AGENT);
}

// ---------------- prep kernels ----------------

__global__ void k_shufA(const float* __restrict__ Wh, const float* __restrict__ Wx,
                        __hip_bfloat16* __restrict__ WA_shuf) {
    int nb = blockIdx.x / 20, kk = blockIdx.x % 20;
    int lane = threadIdx.x;
    int n = nb * 16 + (lane & 15);
    int kbase = kk * 32 + (lane >> 4) * 8;
    size_t o = ((size_t)blockIdx.x * 64 + lane) * 8;
    for (int e = 0; e < 8; ++e) {
        int k = kbase + e;
        float v = (k < 512) ? Wh[(size_t)k * NH + n]
                            : Wx[(size_t)(k - 512) * NH + n];
        WA_shuf[o + e] = __float2bfloat16(v);
    }
}

__global__ void k_shufB(const float* __restrict__ Wh, const float* __restrict__ Wx,
                        const float* __restrict__ Ws, __hip_bfloat16* __restrict__ WB_shuf) {
    int idx = blockIdx.x;                 // jb*180 + g*36 + kk
    int kk = idx % 36, g = (idx / 36) % 5, jb = idx / 180;
    int lane = threadIdx.x;
    int j = jb * 16 + (lane & 15);
    int kbase = kk * 32 + (lane >> 4) * 8;
    size_t o = ((size_t)idx * 64 + lane) * 8;
    for (int e = 0; e < 8; ++e) {
        int k = kbase + e;
        float v;
        if (k < 512)      v = Wh[(size_t)(g + 1) * NH * NH + (size_t)k * NH + j];
        else if (k < 640) v = Wx[(size_t)(g + 1) * ND * NH + (size_t)(k - 512) * NH + j];
        else              v = Ws[(size_t)g * NH * NH + (size_t)(k - 640) * NH + j];
        WB_shuf[o + e] = __float2bfloat16(v);
    }
}

__global__ void k_shufW(const float* __restrict__ Wah, __hip_bfloat16* __restrict__ Wah_shuf) {
    int nb = blockIdx.x / 16, kk = blockIdx.x % 16;
    int lane = threadIdx.x;
    int j = nb * 16 + (lane & 15);
    int kbase = kk * 32 + (lane >> 4) * 8;
    size_t o = ((size_t)blockIdx.x * 64 + lane) * 8;
    for (int e = 0; e < 8; ++e)
        Wah_shuf[o + e] = __float2bfloat16(Wah[(size_t)(kbase + e) * NH + j]);
}

__global__ void k_biases(const float* bh_lin, const float* bx_lin, const float* bst,
                         const float* bs_lin, const float* bg,
                         const float* b_Wh, const float* b_We, const float* b_Wg, const float* bh_p,
                         float* bias_s, float* bias_g, float* bias_fin) {
    int j = threadIdx.x;
    bias_s[j] = bh_lin[j] + bx_lin[j] + bst[j] + bg[j];
    for (int g = 0; g < 5; ++g)
        bias_g[g * NH + j] = bh_lin[(g + 1) * NH + j] + bx_lin[(g + 1) * NH + j] +
                             bs_lin[g * NH + j] + bg[(g + 1) * NH + j];
    bias_fin[j] = b_Wh[j] + b_We[j] + b_Wg[j] + bh_p[j];
}

// per-row init: Dt, A_big[0] (h=0, x=x_0); block 0 zeroes barrier region
__global__ void k_init(const float* __restrict__ X_seq, float* __restrict__ Dt,
                       __hip_bfloat16* __restrict__ A_big, unsigned* __restrict__ bar) {
    int b = blockIdx.x, tid = threadIdx.x;
    if (b == 0) for (int i = tid; i < BAR_TOT; i += 256) bar[i] = 0;
    if (tid < NT) Dt[tid * NB + b] = X_seq[((size_t)b * NT + tid) * (ND + 1) + ND];
    for (int c = tid; c < KKB; c += 256) {
        float v = 0.f;
        if (c >= 512 && c < 640) v = X_seq[(size_t)b * NT * (ND + 1) + (c - 512)];
        A_big[(size_t)b * KKB + c] = __float2bfloat16(v);
    }
}

// ---------------- global fallback barrier (round-6, proven) ----------------
__device__ __forceinline__ void gbar2(unsigned* __restrict__ gb, int wg, unsigned gen) {
    __syncthreads();
    const int tid = threadIdx.x;
    if (tid == 0) st_rel_sys(&gb[wg * 32], gen);
    if (wg == 0) {
        while (ld_rlx_sys(&gb[tid * 32]) < gen) {}
        (void)ld_acq_sys(&gb[tid * 32]);
        __syncthreads();
        if (tid == 0) st_rel_sys(&gb[256 * 32], gen);
    }
    if (tid == 0) {
        while (ld_rlx_sys(&gb[256 * 32]) < gen) {}
        (void)ld_acq_sys(&gb[256 * 32]);
    }
    __syncthreads();
}

// ---------------- intra-XCD barrier (local mode) ----------------
__device__ __forceinline__ void gbarL(unsigned* __restrict__ bar, unsigned xcd, unsigned rank,
                                      unsigned gen) {
    const int tid = threadIdx.x;
    __syncthreads();                                   // data ack'd into local L2
    if (tid == 0) st_rlx_agt(&bar[BAR_MFL + (xcd * 32 + rank) * 16], gen);
    if (rank == 0) {
        if (tid < 32) { while (ld_rlx_agt(&bar[BAR_MFL + (xcd * 32 + tid) * 16]) < gen) {} }
        __syncthreads();
        if (tid == 0) st_rlx_agt(&bar[BAR_DFL + xcd * 32], gen);
    }
    if (tid == 0) {
        while (ld_rlx_agt(&bar[BAR_DFL + xcd * 32]) < gen) {}
        (void)ld_acq_agt(&bar[BAR_DFL + xcd * 32]);    // inv L1 (CU-wide)
    }
    __syncthreads();
}

// ---------------- persistent LSTM kernel: row-split by physical XCD ----------------
// Byte-identical to the round-13/15 passing kernel.

__global__ __launch_bounds__(256, 1) void lstm_coop(
    const float* __restrict__ X_seq, const float* __restrict__ Dt,
    const __hip_bfloat16* __restrict__ WA_shuf, const __hip_bfloat16* __restrict__ WB_shuf,
    const float* __restrict__ bias_s, const float* __restrict__ bias_g,
    const float* __restrict__ Wst,
    __hip_bfloat16* __restrict__ A_big,       // [2][NB][KKB]
    float* __restrict__ c_last, float* __restrict__ s_f32, float* __restrict__ h_last,
    __hip_bfloat16* __restrict__ hist,        // [NMEM][NB][NH]
    unsigned* __restrict__ bar)
{
    const int wg = blockIdx.x;       // 0..255
    const int tid = threadIdx.x;
    const int wv = tid >> 6;         // 0..3
    const int lane = tid & 63;
    const int l15 = lane & 15, lhi = lane >> 4;

    // ---- one-time XCD membership registration ----
    __shared__ unsigned sh_meta[2];
    __shared__ unsigned sh_cnt[8];
    if (tid == 0) {
        unsigned xcc;
        asm volatile("s_getreg_b32 %0, hwreg(HW_REG_XCC_ID)" : "=s"(xcc));
        xcc &= 7u;
        unsigned r = __hip_atomic_fetch_add(&bar[BAR_CNT + xcc], 1u,
                                            __ATOMIC_RELAXED, __HIP_MEMORY_SCOPE_AGENT);
        sh_meta[0] = xcc; sh_meta[1] = r;
    }
    __syncthreads();
    gbar2(bar + BAR_GB, wg, 1u);                 // counts final + visible
    if (tid < 8) sh_cnt[tid] = ld_rlx_sys(&bar[BAR_CNT + tid]);
    __syncthreads();
    bool local_ok = true;
    #pragma unroll
    for (int j = 0; j < 8; ++j) if (sh_cnt[j] != 32u) local_ok = false;

    // local mode: physical XCD grouping; fallback: logical grouping + sys barrier
    const unsigned xcd  = local_ok ? sh_meta[0] : (unsigned)(wg & 7);
    const unsigned rank = local_ok ? sh_meta[1] : (unsigned)(wg >> 3);
    const int row_base  = (int)xcd * 64;         // this group owns rows [row_base, +64)

    const int colj = (int)rank * 16 + l15;       // output column (phase A and B)

    const float ebs  = bias_s[colj];
    const float ewst = Wst[colj];
    float bgc[5];
    #pragma unroll
    for (int g = 0; g < 5; ++g) bgc[g] = bias_g[g * NH + colj];

    const __hip_bfloat16* wa_base = WA_shuf + (size_t)rank * 20 * 512 + lane * 8;
    const __hip_bfloat16* wb_base = WB_shuf + (size_t)rank * 5 * 36 * 512 + lane * 8;

    f32x4 c_reg = {0.f, 0.f, 0.f, 0.f};          // c for rows (wv,lhi,r) x col colj

    for (int t = 0; t < NT; ++t) {
        const int buf = t & 1;
        const __hip_bfloat16* A = A_big + (size_t)buf * NB * KKB;
        __hip_bfloat16* An = A_big + (size_t)(buf ^ 1) * NB * KKB;
        __hip_bfloat16* Aw = A_big + (size_t)buf * NB * KKB;

        // ---- phase A: s = tanh([h|x]@WA + d*Wst + bias_s); 64 rows x 16 cols per WG
        {
            f32x4 acc = {0.f, 0.f, 0.f, 0.f};
            const __hip_bfloat16* arow = A + (size_t)(row_base + wv * 16 + l15) * KKB + lhi * 8;
            #pragma unroll 4
            for (int kk = 0; kk < 20; ++kk) {
                bf16x8 af = *reinterpret_cast<const bf16x8*>(arow + kk * 32);
                bf16x8 bfv = *reinterpret_cast<const bf16x8*>(wa_base + kk * 512);
                acc = __builtin_amdgcn_mfma_f32_16x16x32_bf16(af, bfv, acc, 0, 0, 0);
            }
            #pragma unroll
            for (int r = 0; r < 4; ++r) {
                int row = row_base + wv * 16 + lhi * 4 + r;
                float s = tanhf(acc[r] + ebs + Dt[t * NB + row] * ewst);
                s_f32[row * NH + colj] = s;
                Aw[(size_t)row * KKB + 640 + colj] = __float2bfloat16(s);
            }
        }
        if (local_ok) gbarL(bar, xcd, rank, (unsigned)(2 * t + 1));
        else          gbar2(bar + BAR_GB, wg, (unsigned)(2 * t + 2));

        // ---- phase B: 5 gates; 64 rows x 16 j-cols x 5 gates per WG; fused cell
        {
            f32x4 acc[5] = {};
            const __hip_bfloat16* arow = A + (size_t)(row_base + wv * 16 + l15) * KKB + lhi * 8;
            for (int kk = 0; kk < 36; ++kk) {
                bf16x8 af = *reinterpret_cast<const bf16x8*>(arow + kk * 32);
                #pragma unroll
                for (int g = 0; g < 5; ++g) {
                    bf16x8 bfv = *reinterpret_cast<const bf16x8*>(wb_base + (g * 36 + kk) * 512);
                    acc[g] = __builtin_amdgcn_mfma_f32_16x16x32_bf16(af, bfv, acc[g], 0, 0, 0);
                }
            }
            #pragma unroll
            for (int r = 0; r < 4; ++r) {
                int row = row_base + wv * 16 + lhi * 4 + r;
                float f  = sigm_(acc[0][r] + bgc[0]);
                float i  = sigm_(acc[1][r] + bgc[1]);
                float Tg = sigm_(acc[2][r] + bgc[2]);
                float z  = tanhf(acc[3][r] + bgc[3]);
                float o  = sigm_(acc[4][r] + bgc[4]);
                float sv = s_f32[row * NH + colj];
                float cn = f * c_reg[r] + i * z + Tg * sv;
                c_reg[r] = cn;
                float hn = o * tanhf(cn);
                An[(size_t)row * KKB + colj] = __float2bfloat16(hn);
                if (t >= NT - NMEM)
                    hist[((size_t)(t - (NT - NMEM)) * NB + row) * NH + colj] = __float2bfloat16(hn);
                if (t == NT - 1) {
                    h_last[row * NH + colj] = hn;
                    c_last[row * NH + colj] = cn;
                }
            }
            // stage x_{t+1} for this group's 64 rows: 32 WGs x 256 threads = 8192 elems
            if (t < NT - 1) {
                int idx = (int)rank * 256 + tid;    // 0..8191
                int rr = idx >> 7, d = idx & 127;
                int row = row_base + rr;
                float xv = X_seq[((size_t)row * NT + (t + 1)) * (ND + 1) + d];
                An[(size_t)row * KKB + 512 + d] = __float2bfloat16(xv);
            }
        }
        if (local_ok) gbarL(bar, xcd, rank, (unsigned)(2 * t + 2));
        else          gbar2(bar + BAR_GB, wg, (unsigned)(2 * t + 3));
    }
}

// ---------------- attention + head ----------------

__global__ void k_qa(const float* __restrict__ h_last, const float* __restrict__ c_last,
                     const float* __restrict__ Waq, const float* __restrict__ baq,
                     float* __restrict__ qa) {
    __shared__ float qs[8][1024];
    int b0 = blockIdx.x * 8;
    for (int idx = threadIdx.x; idx < 8 * 1024; idx += 512) {
        int bb = idx >> 10, k = idx & 1023;
        qs[bb][k] = (k < 512) ? h_last[(b0 + bb) * NH + k] : c_last[(b0 + bb) * NH + (k - 512)];
    }
    __syncthreads();
    int j = threadIdx.x;
    float acc[8] = {};
    for (int k = 0; k < 1024; ++k) {
        float w = Waq[(size_t)k * NH + j];
        #pragma unroll
        for (int bb = 0; bb < 8; ++bb) acc[bb] += qs[bb][k] * w;
    }
    float bq = baq[j];
    for (int bb = 0; bb < 8; ++bb) qa[(b0 + bb) * NH + j] = acc[bb] + bq;
}

// v2: one block per rt (512 blocks); hist A-fragments hoisted to registers once,
// jt looped internally. Per-accumulator math order and score_part layout are
// identical to the previous (512,8)-grid version -> bit-identical output.
__global__ void k_scores(const __hip_bfloat16* __restrict__ hist,
                         const __hip_bfloat16* __restrict__ Wah_shuf,
                         const float* __restrict__ qa, const float* __restrict__ bah,
                         const float* __restrict__ vt, float* __restrict__ score_part) {
    int rt = blockIdx.x;
    int tid = threadIdx.x, wv = tid >> 6, lane = tid & 63;
    int l15 = lane & 15, lhi = lane >> 4;
    int R0 = rt * 64 + wv * 16;
    const __hip_bfloat16* arow = hist + (size_t)(R0 + l15) * NH + lhi * 8;
    bf16x8 af[16];
    #pragma unroll
    for (int kk = 0; kk < 16; ++kk)
        af[kk] = *reinterpret_cast<const bf16x8*>(arow + kk * 32);
    const __hip_bfloat16* bbase = Wah_shuf + lane * 8;
    for (int jt = 0; jt < 8; ++jt) {
        f32x4 acc[4] = {};
        for (int kk = 0; kk < 16; ++kk) {
            #pragma unroll
            for (int f = 0; f < 4; ++f) {
                int nb = jt * 4 + f;
                bf16x8 bfv = *reinterpret_cast<const bf16x8*>(bbase + (size_t)(nb * 16 + kk) * 512);
                acc[f] = __builtin_amdgcn_mfma_f32_16x16x32_bf16(af[kk], bfv, acc[f], 0, 0, 0);
            }
        }
        float part[4] = {};
        #pragma unroll
        for (int r = 0; r < 4; ++r) {
            int R = R0 + lhi * 4 + r;
            int b = R & (NB - 1);
            #pragma unroll
            for (int f = 0; f < 4; ++f) {
                int j = (jt * 4 + f) * 16 + l15;
                float v = acc[f][r] + qa[b * NH + j] + bah[j];
                part[r] += tanhf(v) * vt[j];
            }
        }
        #pragma unroll
        for (int m = 1; m <= 8; m <<= 1)
            #pragma unroll
            for (int r = 0; r < 4; ++r) part[r] += __shfl_xor(part[r], m);
        if (l15 == 0)
            #pragma unroll
            for (int r = 0; r < 4; ++r)
                score_part[(size_t)jt * (NMEM * NB) + R0 + lhi * 4 + r] = part[r];
    }
}

// v2: 256 threads (softmax on wave 0, identical math; e-pass parallelized over j
// with the same ascending-mm accumulation -> bit-identical e_buf).
__global__ void k_softmax_e(const float* __restrict__ score_part,
                            const __hip_bfloat16* __restrict__ hist,
                            float* __restrict__ e_buf) {
    int b = blockIdx.x, tid = threadIdx.x;  // 256 threads
    __shared__ float al[64];
    if (tid < 64) {
        int m = tid;
        float sc = 0.f;
        for (int p = 0; p < 8; ++p) sc += score_part[(size_t)p * (NMEM * NB) + m * NB + b];
        float mx = sc;
        for (int off = 32; off; off >>= 1) mx = fmaxf(mx, __shfl_xor(mx, off));
        float ex = expf(sc - mx);
        float sm = ex;
        for (int off = 32; off; off >>= 1) sm += __shfl_xor(sm, off);
        al[m] = ex / sm;
    }
    __syncthreads();
    for (int j0 = 0; j0 < NH; j0 += 256) {
        int j = j0 + tid;
        float acc = 0.f;
        for (int mm = 0; mm < 64; ++mm)
            acc += al[mm] * __bfloat162float(hist[((size_t)mm * NB + b) * NH + j]);
        e_buf[b * NH + j] = acc;
    }
}

__global__ void k_final(const float* __restrict__ h_last, const float* __restrict__ e_buf,
                        const float* __restrict__ X_seq, const float* __restrict__ W_h,
                        const float* __restrict__ We, const float* __restrict__ Wg,
                        const float* __restrict__ bias_fin, float* __restrict__ h_fin) {
    __shared__ float hs[8][512], es[8][512], xs[8][128];
    int b0 = blockIdx.x * 8;
    for (int idx = threadIdx.x; idx < 8 * 512; idx += 512) {
        int bb = idx >> 9, k = idx & 511;
        hs[bb][k] = h_last[(b0 + bb) * NH + k];
        es[bb][k] = e_buf[(b0 + bb) * NH + k];
    }
    for (int idx = threadIdx.x; idx < 8 * 128; idx += 512) {
        int bb = idx >> 7, d = idx & 127;
        xs[bb][d] = X_seq[((size_t)(b0 + bb) * NT + (NT - 1)) * (ND + 1) + d];
    }
    __syncthreads();
    int j = threadIdx.x;
    float acc[8];
    float bfv = bias_fin[j];
    #pragma unroll
    for (int bb = 0; bb < 8; ++bb) acc[bb] = bfv;
    for (int k = 0; k < 512; ++k) {
        float w = W_h[(size_t)k * NH + j];
        #pragma unroll
        for (int bb = 0; bb < 8; ++bb) acc[bb] += hs[bb][k] * w;
    }
    for (int k = 0; k < 512; ++k) {
        float w = We[(size_t)k * NH + j];
        #pragma unroll
        for (int bb = 0; bb < 8; ++bb) acc[bb] += es[bb][k] * w;
    }
    for (int d = 0; d < 128; ++d) {
        float w = Wg[(size_t)d * NH + j];
        #pragma unroll
        for (int bb = 0; bb < 8; ++bb) acc[bb] += xs[bb][d] * w;
    }
    for (int bb = 0; bb < 8; ++bb) h_fin[(b0 + bb) * NH + j] = tanhf(acc[bb]);
}

__global__ void k_out(const float* __restrict__ h_fin, const float* __restrict__ Wc,
                      const float* __restrict__ bc, float* __restrict__ out) {
    int b = blockIdx.x, tid = threadIdx.x;  // 256 threads
    float p = 0.f;
    for (int j = tid; j < NH; j += 256) p += h_fin[b * NH + j] * Wc[j];
    for (int off = 32; off; off >>= 1) p += __shfl_xor(p, off);
    __shared__ float red[4];
    if ((tid & 63) == 0) red[tid >> 6] = p;
    __syncthreads();
    if (tid == 0) out[b] = 1.f / (1.f + expf(-(red[0] + red[1] + red[2] + red[3] + bc[0])));
}

// ---------------- launch ----------------

extern "C" void kernel_launch(void* const* d_in, const int* in_sizes, int n_in,
                              void* d_out, int out_size, void* d_ws, size_t ws_size,
                              hipStream_t stream) {
    const float* X_seq  = (const float*)d_in[0];
    const float* Wh     = (const float*)d_in[1];
    const float* bh_lin = (const float*)d_in[2];
    const float* Wx     = (const float*)d_in[3];
    const float* bx_lin = (const float*)d_in[4];
    const float* Wst    = (const float*)d_in[5];
    const float* bst    = (const float*)d_in[6];
    const float* Ws     = (const float*)d_in[7];
    const float* bs_lin = (const float*)d_in[8];
    const float* bg     = (const float*)d_in[9];
    const float* Waq    = (const float*)d_in[10];
    const float* baq    = (const float*)d_in[11];
    const float* Wah    = (const float*)d_in[12];
    const float* bah    = (const float*)d_in[13];
    const float* vt     = (const float*)d_in[14];
    const float* W_h    = (const float*)d_in[15];
    const float* b_Wh   = (const float*)d_in[16];
    const float* We     = (const float*)d_in[17];
    const float* b_We   = (const float*)d_in[18];
    const float* Wg     = (const float*)d_in[19];
    const float* b_Wg   = (const float*)d_in[20];
    const float* bh_p   = (const float*)d_in[21];
    const float* Wc     = (const float*)d_in[22];
    const float* bc     = (const float*)d_in[23];
    float* out = (float*)d_out;

    char* ws = (char*)d_ws;
    size_t off = 0;
    auto alloc = [&](size_t bytes) -> char* {
        char* p = ws + off;
        off = (off + bytes + 255) & ~(size_t)255;
        return p;
    };
    __hip_bfloat16* WA_shuf  = (__hip_bfloat16*)alloc((size_t)KKA * NH * 2);
    __hip_bfloat16* WB_shuf  = (__hip_bfloat16*)alloc((size_t)KKB * 5 * NH * 2);
    __hip_bfloat16* Wah_shuf = (__hip_bfloat16*)alloc((size_t)NH * NH * 2);
    float* bias_s   = (float*)alloc(NH * 4);
    float* bias_g   = (float*)alloc(5 * NH * 4);
    float* bias_fin = (float*)alloc(NH * 4);
    float* Dt       = (float*)alloc((size_t)NT * NB * 4);
    __hip_bfloat16* A_big = (__hip_bfloat16*)alloc((size_t)2 * NB * KKB * 2);
    float* c_last   = (float*)alloc((size_t)NB * NH * 4);
    float* s_f32    = (float*)alloc((size_t)NB * NH * 4);
    float* h_last   = (float*)alloc((size_t)NB * NH * 4);
    __hip_bfloat16* hist = (__hip_bfloat16*)alloc((size_t)NMEM * NB * NH * 2);
    float* qa       = (float*)alloc((size_t)NB * NH * 4);
    float* score_part = (float*)alloc((size_t)8 * NMEM * NB * 4);
    float* e_buf    = (float*)alloc((size_t)NB * NH * 4);
    float* h_fin    = (float*)alloc((size_t)NB * NH * 4);
    unsigned* bar   = (unsigned*)alloc((size_t)BAR_TOT * 4 + 4096);

    // prep
    hipLaunchKernelGGL(k_shufA, dim3(32 * 20), dim3(64), 0, stream, Wh, Wx, WA_shuf);
    hipLaunchKernelGGL(k_shufB, dim3(32 * 5 * 36), dim3(64), 0, stream, Wh, Wx, Ws, WB_shuf);
    hipLaunchKernelGGL(k_shufW, dim3(32 * 16), dim3(64), 0, stream, Wah, Wah_shuf);
    hipLaunchKernelGGL(k_biases, dim3(1), dim3(512), 0, stream,
                       bh_lin, bx_lin, bst, bs_lin, bg, b_Wh, b_We, b_Wg, bh_p,
                       bias_s, bias_g, bias_fin);
    hipLaunchKernelGGL(k_init, dim3(NB), dim3(256), 0, stream, X_seq, Dt, A_big, bar);

    // persistent recurrent kernel (cooperative launch for co-residency guarantee)
    {
        void* args[] = {(void*)&X_seq, (void*)&Dt, (void*)&WA_shuf, (void*)&WB_shuf,
                        (void*)&bias_s, (void*)&bias_g, (void*)&Wst, (void*)&A_big,
                        (void*)&c_last, (void*)&s_f32, (void*)&h_last, (void*)&hist,
                        (void*)&bar};
        hipLaunchCooperativeKernel((void*)lstm_coop, dim3(256), dim3(256), args, 0, stream);
    }

    // attention + head
    hipLaunchKernelGGL(k_qa, dim3(64), dim3(512), 0, stream, h_last, c_last, Waq, baq, qa);
    hipLaunchKernelGGL(k_scores, dim3(512), dim3(256), 0, stream,
                       hist, Wah_shuf, qa, bah, vt, score_part);
    hipLaunchKernelGGL(k_softmax_e, dim3(NB), dim3(256), 0, stream, score_part, hist, e_buf);
    hipLaunchKernelGGL(k_final, dim3(64), dim3(512), 0, stream,
                       h_last, e_buf, X_seq, W_h, We, Wg, bias_fin, h_fin);
    hipLaunchKernelGGL(k_out, dim3(NB), dim3(256), 0, stream, h_fin, Wc, bc, out);
}

// Round 17
// 3841.496 us; speedup vs baseline: 1.5434x; 1.0007x over previous
//
#include <hip/hip_runtime.h>
#include <hip/hip_bf16.h>

typedef __bf16 bf16x8 __attribute__((ext_vector_type(8)));
typedef float f32x4 __attribute__((ext_vector_type(4)));

constexpr int NB   = 512;   // batch
constexpr int NT   = 128;   // timesteps
constexpr int ND   = 128;   // input dim
constexpr int NH   = 512;   // hidden
constexpr int NMEM = 64;    // attention memory
constexpr int KKA  = 640;   // h(512)+x(128)
constexpr int KKB  = 1152;  // h(512)+x(128)+s(512)

// barrier region layout (u32 indices)
constexpr int BAR_CNT = 0;        // [8] per-XCD member counts
constexpr int BAR_GB  = 64;       // [257] stride 32: global fallback/setup barrier flags
constexpr int BAR_MFL = 8448;     // [8][32] stride 16: per-XCD member flags
constexpr int BAR_DFL = 12800;    // [8] stride 32: per-XCD done flags
constexpr int BAR_TOT = 16384;

__device__ __forceinline__ float sigm_(float x) { return 1.f / (1.f + expf(-x)); }

// ---- atomic helpers ----
__device__ __forceinline__ unsigned ld_rlx_sys(const unsigned* p) {
    return __hip_atomic_load(p, __ATOMIC_RELAXED, __HIP_MEMORY_SCOPE_SYSTEM);
}
__device__ __forceinline__ unsigned ld_acq_sys(const unsigned* p) {
    return __hip_atomic_load(p, __ATOMIC_ACQUIRE, __HIP_MEMORY_SCOPE_SYSTEM);
}
__device__ __forceinline__ void st_rel_sys(unsigned* p, unsigned v) {
    __hip_atomic_store(p, v, __ATOMIC_RELEASE, __HIP_MEMORY_SCOPE_SYSTEM);
}
__device__ __forceinline__ unsigned ld_rlx_agt(const unsigned* p) {
    return __hip_atomic_load(p, __ATOMIC_RELAXED, __HIP_MEMORY_SCOPE_AGENT);
}
__device__ __forceinline__ unsigned ld_acq_agt(const unsigned* p) {
    return __hip_atomic_load(p, __ATOMIC_ACQUIRE, __HIP_MEMORY_SCOPE_AGENT);
}
__device__ __forceinline__ void st_rlx_agt(unsigned* p, unsigned v) {
    __hip_atomic_store(p, v, __ATOMIC_RELAXED, __HIP_MEMORY_SCOPE_AGENT);
}

// ---------------- merged prep kernel ----------------
// blocks [0,5760): WB_shuf; [5760,6400): WA_shuf; [6400,6912): Wah_shuf;
// [6912,6920): fused biases. Disjoint outputs, per-element math identical to
// the previous 4 separate kernels -> bit-identical buffers.
__global__ void k_prep(const float* __restrict__ Wh, const float* __restrict__ Wx,
                       const float* __restrict__ Ws, const float* __restrict__ Wah,
                       const float* __restrict__ bh_lin, const float* __restrict__ bx_lin,
                       const float* __restrict__ bst, const float* __restrict__ bs_lin,
                       const float* __restrict__ bg, const float* __restrict__ b_Wh,
                       const float* __restrict__ b_We, const float* __restrict__ b_Wg,
                       const float* __restrict__ bh_p,
                       __hip_bfloat16* __restrict__ WA_shuf, __hip_bfloat16* __restrict__ WB_shuf,
                       __hip_bfloat16* __restrict__ Wah_shuf,
                       float* __restrict__ bias_s, float* __restrict__ bias_g,
                       float* __restrict__ bias_fin) {
    int bid = blockIdx.x;
    int lane = threadIdx.x;
    if (bid < 5760) {                                  // WB_shuf
        int idx = bid;                                 // jb*180 + g*36 + kk
        int kk = idx % 36, g = (idx / 36) % 5, jb = idx / 180;
        int j = jb * 16 + (lane & 15);
        int kbase = kk * 32 + (lane >> 4) * 8;
        size_t o = ((size_t)idx * 64 + lane) * 8;
        for (int e = 0; e < 8; ++e) {
            int k = kbase + e;
            float v;
            if (k < 512)      v = Wh[(size_t)(g + 1) * NH * NH + (size_t)k * NH + j];
            else if (k < 640) v = Wx[(size_t)(g + 1) * ND * NH + (size_t)(k - 512) * NH + j];
            else              v = Ws[(size_t)g * NH * NH + (size_t)(k - 640) * NH + j];
            WB_shuf[o + e] = __float2bfloat16(v);
        }
    } else if (bid < 6400) {                           // WA_shuf
        int idx = bid - 5760;
        int nb = idx / 20, kk = idx % 20;
        int n = nb * 16 + (lane & 15);
        int kbase = kk * 32 + (lane >> 4) * 8;
        size_t o = ((size_t)idx * 64 + lane) * 8;
        for (int e = 0; e < 8; ++e) {
            int k = kbase + e;
            float v = (k < 512) ? Wh[(size_t)k * NH + n]
                                : Wx[(size_t)(k - 512) * NH + n];
            WA_shuf[o + e] = __float2bfloat16(v);
        }
    } else if (bid < 6912) {                           // Wah_shuf
        int idx = bid - 6400;
        int nb = idx / 16, kk = idx % 16;
        int j = nb * 16 + (lane & 15);
        int kbase = kk * 32 + (lane >> 4) * 8;
        size_t o = ((size_t)idx * 64 + lane) * 8;
        for (int e = 0; e < 8; ++e)
            Wah_shuf[o + e] = __float2bfloat16(Wah[(size_t)(kbase + e) * NH + j]);
    } else {                                           // fused biases
        int j = (bid - 6912) * 64 + lane;
        bias_s[j] = bh_lin[j] + bx_lin[j] + bst[j] + bg[j];
        for (int g = 0; g < 5; ++g)
            bias_g[g * NH + j] = bh_lin[(g + 1) * NH + j] + bx_lin[(g + 1) * NH + j] +
                                 bs_lin[g * NH + j] + bg[(g + 1) * NH + j];
        bias_fin[j] = b_Wh[j] + b_We[j] + b_Wg[j] + bh_p[j];
    }
}

// per-row init: Dt, A_big[0] (h=0, x=x_0); block 0 zeroes barrier region
__global__ void k_init(const float* __restrict__ X_seq, float* __restrict__ Dt,
                       __hip_bfloat16* __restrict__ A_big, unsigned* __restrict__ bar) {
    int b = blockIdx.x, tid = threadIdx.x;
    if (b == 0) for (int i = tid; i < BAR_TOT; i += 256) bar[i] = 0;
    if (tid < NT) Dt[tid * NB + b] = X_seq[((size_t)b * NT + tid) * (ND + 1) + ND];
    for (int c = tid; c < KKB; c += 256) {
        float v = 0.f;
        if (c >= 512 && c < 640) v = X_seq[(size_t)b * NT * (ND + 1) + (c - 512)];
        A_big[(size_t)b * KKB + c] = __float2bfloat16(v);
    }
}

// ---------------- global fallback barrier (round-6, proven) ----------------
__device__ __forceinline__ void gbar2(unsigned* __restrict__ gb, int wg, unsigned gen) {
    __syncthreads();
    const int tid = threadIdx.x;
    if (tid == 0) st_rel_sys(&gb[wg * 32], gen);
    if (wg == 0) {
        while (ld_rlx_sys(&gb[tid * 32]) < gen) {}
        (void)ld_acq_sys(&gb[tid * 32]);
        __syncthreads();
        if (tid == 0) st_rel_sys(&gb[256 * 32], gen);
    }
    if (tid == 0) {
        while (ld_rlx_sys(&gb[256 * 32]) < gen) {}
        (void)ld_acq_sys(&gb[256 * 32]);
    }
    __syncthreads();
}

// ---------------- intra-XCD barrier (local mode) ----------------
__device__ __forceinline__ void gbarL(unsigned* __restrict__ bar, unsigned xcd, unsigned rank,
                                      unsigned gen) {
    const int tid = threadIdx.x;
    __syncthreads();                                   // data ack'd into local L2
    if (tid == 0) st_rlx_agt(&bar[BAR_MFL + (xcd * 32 + rank) * 16], gen);
    if (rank == 0) {
        if (tid < 32) { while (ld_rlx_agt(&bar[BAR_MFL + (xcd * 32 + tid) * 16]) < gen) {} }
        __syncthreads();
        if (tid == 0) st_rlx_agt(&bar[BAR_DFL + xcd * 32], gen);
    }
    if (tid == 0) {
        while (ld_rlx_agt(&bar[BAR_DFL + xcd * 32]) < gen) {}
        (void)ld_acq_agt(&bar[BAR_DFL + xcd * 32]);    // inv L1 (CU-wide)
    }
    __syncthreads();
}

// ---------------- persistent LSTM kernel: row-split by physical XCD ----------------
// Byte-identical to the round-13/15/16 passing kernel.

__global__ __launch_bounds__(256, 1) void lstm_coop(
    const float* __restrict__ X_seq, const float* __restrict__ Dt,
    const __hip_bfloat16* __restrict__ WA_shuf, const __hip_bfloat16* __restrict__ WB_shuf,
    const float* __restrict__ bias_s, const float* __restrict__ bias_g,
    const float* __restrict__ Wst,
    __hip_bfloat16* __restrict__ A_big,       // [2][NB][KKB]
    float* __restrict__ c_last, float* __restrict__ s_f32, float* __restrict__ h_last,
    __hip_bfloat16* __restrict__ hist,        // [NMEM][NB][NH]
    unsigned* __restrict__ bar)
{
    const int wg = blockIdx.x;       // 0..255
    const int tid = threadIdx.x;
    const int wv = tid >> 6;         // 0..3
    const int lane = tid & 63;
    const int l15 = lane & 15, lhi = lane >> 4;

    // ---- one-time XCD membership registration ----
    __shared__ unsigned sh_meta[2];
    __shared__ unsigned sh_cnt[8];
    if (tid == 0) {
        unsigned xcc;
        asm volatile("s_getreg_b32 %0, hwreg(HW_REG_XCC_ID)" : "=s"(xcc));
        xcc &= 7u;
        unsigned r = __hip_atomic_fetch_add(&bar[BAR_CNT + xcc], 1u,
                                            __ATOMIC_RELAXED, __HIP_MEMORY_SCOPE_AGENT);
        sh_meta[0] = xcc; sh_meta[1] = r;
    }
    __syncthreads();
    gbar2(bar + BAR_GB, wg, 1u);                 // counts final + visible
    if (tid < 8) sh_cnt[tid] = ld_rlx_sys(&bar[BAR_CNT + tid]);
    __syncthreads();
    bool local_ok = true;
    #pragma unroll
    for (int j = 0; j < 8; ++j) if (sh_cnt[j] != 32u) local_ok = false;

    // local mode: physical XCD grouping; fallback: logical grouping + sys barrier
    const unsigned xcd  = local_ok ? sh_meta[0] : (unsigned)(wg & 7);
    const unsigned rank = local_ok ? sh_meta[1] : (unsigned)(wg >> 3);
    const int row_base  = (int)xcd * 64;         // this group owns rows [row_base, +64)

    const int colj = (int)rank * 16 + l15;       // output column (phase A and B)

    const float ebs  = bias_s[colj];
    const float ewst = Wst[colj];
    float bgc[5];
    #pragma unroll
    for (int g = 0; g < 5; ++g) bgc[g] = bias_g[g * NH + colj];

    const __hip_bfloat16* wa_base = WA_shuf + (size_t)rank * 20 * 512 + lane * 8;
    const __hip_bfloat16* wb_base = WB_shuf + (size_t)rank * 5 * 36 * 512 + lane * 8;

    f32x4 c_reg = {0.f, 0.f, 0.f, 0.f};          // c for rows (wv,lhi,r) x col colj

    for (int t = 0; t < NT; ++t) {
        const int buf = t & 1;
        const __hip_bfloat16* A = A_big + (size_t)buf * NB * KKB;
        __hip_bfloat16* An = A_big + (size_t)(buf ^ 1) * NB * KKB;
        __hip_bfloat16* Aw = A_big + (size_t)buf * NB * KKB;

        // ---- phase A: s = tanh([h|x]@WA + d*Wst + bias_s); 64 rows x 16 cols per WG
        {
            f32x4 acc = {0.f, 0.f, 0.f, 0.f};
            const __hip_bfloat16* arow = A + (size_t)(row_base + wv * 16 + l15) * KKB + lhi * 8;
            #pragma unroll 4
            for (int kk = 0; kk < 20; ++kk) {
                bf16x8 af = *reinterpret_cast<const bf16x8*>(arow + kk * 32);
                bf16x8 bfv = *reinterpret_cast<const bf16x8*>(wa_base + kk * 512);
                acc = __builtin_amdgcn_mfma_f32_16x16x32_bf16(af, bfv, acc, 0, 0, 0);
            }
            #pragma unroll
            for (int r = 0; r < 4; ++r) {
                int row = row_base + wv * 16 + lhi * 4 + r;
                float s = tanhf(acc[r] + ebs + Dt[t * NB + row] * ewst);
                s_f32[row * NH + colj] = s;
                Aw[(size_t)row * KKB + 640 + colj] = __float2bfloat16(s);
            }
        }
        if (local_ok) gbarL(bar, xcd, rank, (unsigned)(2 * t + 1));
        else          gbar2(bar + BAR_GB, wg, (unsigned)(2 * t + 2));

        // ---- phase B: 5 gates; 64 rows x 16 j-cols x 5 gates per WG; fused cell
        {
            f32x4 acc[5] = {};
            const __hip_bfloat16* arow = A + (size_t)(row_base + wv * 16 + l15) * KKB + lhi * 8;
            for (int kk = 0; kk < 36; ++kk) {
                bf16x8 af = *reinterpret_cast<const bf16x8*>(arow + kk * 32);
                #pragma unroll
                for (int g = 0; g < 5; ++g) {
                    bf16x8 bfv = *reinterpret_cast<const bf16x8*>(wb_base + (g * 36 + kk) * 512);
                    acc[g] = __builtin_amdgcn_mfma_f32_16x16x32_bf16(af, bfv, acc[g], 0, 0, 0);
                }
            }
            #pragma unroll
            for (int r = 0; r < 4; ++r) {
                int row = row_base + wv * 16 + lhi * 4 + r;
                float f  = sigm_(acc[0][r] + bgc[0]);
                float i  = sigm_(acc[1][r] + bgc[1]);
                float Tg = sigm_(acc[2][r] + bgc[2]);
                float z  = tanhf(acc[3][r] + bgc[3]);
                float o  = sigm_(acc[4][r] + bgc[4]);
                float sv = s_f32[row * NH + colj];
                float cn = f * c_reg[r] + i * z + Tg * sv;
                c_reg[r] = cn;
                float hn = o * tanhf(cn);
                An[(size_t)row * KKB + colj] = __float2bfloat16(hn);
                if (t >= NT - NMEM)
                    hist[((size_t)(t - (NT - NMEM)) * NB + row) * NH + colj] = __float2bfloat16(hn);
                if (t == NT - 1) {
                    h_last[row * NH + colj] = hn;
                    c_last[row * NH + colj] = cn;
                }
            }
            // stage x_{t+1} for this group's 64 rows: 32 WGs x 256 threads = 8192 elems
            if (t < NT - 1) {
                int idx = (int)rank * 256 + tid;    // 0..8191
                int rr = idx >> 7, d = idx & 127;
                int row = row_base + rr;
                float xv = X_seq[((size_t)row * NT + (t + 1)) * (ND + 1) + d];
                An[(size_t)row * KKB + 512 + d] = __float2bfloat16(xv);
            }
        }
        if (local_ok) gbarL(bar, xcd, rank, (unsigned)(2 * t + 2));
        else          gbar2(bar + BAR_GB, wg, (unsigned)(2 * t + 3));
    }
}

// ---------------- attention + head ----------------

// v2: 16 batch rows per block (32 blocks) — halves per-block-replicated Waq
// traffic; per-output ascending-k accumulation unchanged -> bit-identical qa.
__global__ void k_qa(const float* __restrict__ h_last, const float* __restrict__ c_last,
                     const float* __restrict__ Waq, const float* __restrict__ baq,
                     float* __restrict__ qa) {
    __shared__ float qs[16][1024];
    int b0 = blockIdx.x * 16;
    for (int idx = threadIdx.x; idx < 16 * 1024; idx += 512) {
        int bb = idx >> 10, k = idx & 1023;
        qs[bb][k] = (k < 512) ? h_last[(b0 + bb) * NH + k] : c_last[(b0 + bb) * NH + (k - 512)];
    }
    __syncthreads();
    int j = threadIdx.x;
    float acc[16] = {};
    for (int k = 0; k < 1024; ++k) {
        float w = Waq[(size_t)k * NH + j];
        #pragma unroll
        for (int bb = 0; bb < 16; ++bb) acc[bb] += qs[bb][k] * w;
    }
    float bq = baq[j];
    for (int bb = 0; bb < 16; ++bb) qa[(b0 + bb) * NH + j] = acc[bb] + bq;
}

// v2: one block per rt (512 blocks); hist A-fragments hoisted to registers once,
// jt looped internally. Bit-identical output.
__global__ void k_scores(const __hip_bfloat16* __restrict__ hist,
                         const __hip_bfloat16* __restrict__ Wah_shuf,
                         const float* __restrict__ qa, const float* __restrict__ bah,
                         const float* __restrict__ vt, float* __restrict__ score_part) {
    int rt = blockIdx.x;
    int tid = threadIdx.x, wv = tid >> 6, lane = tid & 63;
    int l15 = lane & 15, lhi = lane >> 4;
    int R0 = rt * 64 + wv * 16;
    const __hip_bfloat16* arow = hist + (size_t)(R0 + l15) * NH + lhi * 8;
    bf16x8 af[16];
    #pragma unroll
    for (int kk = 0; kk < 16; ++kk)
        af[kk] = *reinterpret_cast<const bf16x8*>(arow + kk * 32);
    const __hip_bfloat16* bbase = Wah_shuf + lane * 8;
    for (int jt = 0; jt < 8; ++jt) {
        f32x4 acc[4] = {};
        for (int kk = 0; kk < 16; ++kk) {
            #pragma unroll
            for (int f = 0; f < 4; ++f) {
                int nb = jt * 4 + f;
                bf16x8 bfv = *reinterpret_cast<const bf16x8*>(bbase + (size_t)(nb * 16 + kk) * 512);
                acc[f] = __builtin_amdgcn_mfma_f32_16x16x32_bf16(af[kk], bfv, acc[f], 0, 0, 0);
            }
        }
        float part[4] = {};
        #pragma unroll
        for (int r = 0; r < 4; ++r) {
            int R = R0 + lhi * 4 + r;
            int b = R & (NB - 1);
            #pragma unroll
            for (int f = 0; f < 4; ++f) {
                int j = (jt * 4 + f) * 16 + l15;
                float v = acc[f][r] + qa[b * NH + j] + bah[j];
                part[r] += tanhf(v) * vt[j];
            }
        }
        #pragma unroll
        for (int m = 1; m <= 8; m <<= 1)
            #pragma unroll
            for (int r = 0; r < 4; ++r) part[r] += __shfl_xor(part[r], m);
        if (l15 == 0)
            #pragma unroll
            for (int r = 0; r < 4; ++r)
                score_part[(size_t)jt * (NMEM * NB) + R0 + lhi * 4 + r] = part[r];
    }
}

// v2: 256 threads (softmax on wave 0, identical math; e-pass parallelized over j
// with the same ascending-mm accumulation -> bit-identical e_buf).
__global__ void k_softmax_e(const float* __restrict__ score_part,
                            const __hip_bfloat16* __restrict__ hist,
                            float* __restrict__ e_buf) {
    int b = blockIdx.x, tid = threadIdx.x;  // 256 threads
    __shared__ float al[64];
    if (tid < 64) {
        int m = tid;
        float sc = 0.f;
        for (int p = 0; p < 8; ++p) sc += score_part[(size_t)p * (NMEM * NB) + m * NB + b];
        float mx = sc;
        for (int off = 32; off; off >>= 1) mx = fmaxf(mx, __shfl_xor(mx, off));
        float ex = expf(sc - mx);
        float sm = ex;
        for (int off = 32; off; off >>= 1) sm += __shfl_xor(sm, off);
        al[m] = ex / sm;
    }
    __syncthreads();
    for (int j0 = 0; j0 < NH; j0 += 256) {
        int j = j0 + tid;
        float acc = 0.f;
        for (int mm = 0; mm < 64; ++mm)
            acc += al[mm] * __bfloat162float(hist[((size_t)mm * NB + b) * NH + j]);
        e_buf[b * NH + j] = acc;
    }
}

__global__ void k_final(const float* __restrict__ h_last, const float* __restrict__ e_buf,
                        const float* __restrict__ X_seq, const float* __restrict__ W_h,
                        const float* __restrict__ We, const float* __restrict__ Wg,
                        const float* __restrict__ bias_fin, float* __restrict__ h_fin) {
    __shared__ float hs[8][512], es[8][512], xs[8][128];
    int b0 = blockIdx.x * 8;
    for (int idx = threadIdx.x; idx < 8 * 512; idx += 512) {
        int bb = idx >> 9, k = idx & 511;
        hs[bb][k] = h_last[(b0 + bb) * NH + k];
        es[bb][k] = e_buf[(b0 + bb) * NH + k];
    }
    for (int idx = threadIdx.x; idx < 8 * 128; idx += 512) {
        int bb = idx >> 7, d = idx & 127;
        xs[bb][d] = X_seq[((size_t)(b0 + bb) * NT + (NT - 1)) * (ND + 1) + d];
    }
    __syncthreads();
    int j = threadIdx.x;
    float acc[8];
    float bfv = bias_fin[j];
    #pragma unroll
    for (int bb = 0; bb < 8; ++bb) acc[bb] = bfv;
    for (int k = 0; k < 512; ++k) {
        float w = W_h[(size_t)k * NH + j];
        #pragma unroll
        for (int bb = 0; bb < 8; ++bb) acc[bb] += hs[bb][k] * w;
    }
    for (int k = 0; k < 512; ++k) {
        float w = We[(size_t)k * NH + j];
        #pragma unroll
        for (int bb = 0; bb < 8; ++bb) acc[bb] += es[bb][k] * w;
    }
    for (int d = 0; d < 128; ++d) {
        float w = Wg[(size_t)d * NH + j];
        #pragma unroll
        for (int bb = 0; bb < 8; ++bb) acc[bb] += xs[bb][d] * w;
    }
    for (int bb = 0; bb < 8; ++bb) h_fin[(b0 + bb) * NH + j] = tanhf(acc[bb]);
}

__global__ void k_out(const float* __restrict__ h_fin, const float* __restrict__ Wc,
                      const float* __restrict__ bc, float* __restrict__ out) {
    int b = blockIdx.x, tid = threadIdx.x;  // 256 threads
    float p = 0.f;
    for (int j = tid; j < NH; j += 256) p += h_fin[b * NH + j] * Wc[j];
    for (int off = 32; off; off >>= 1) p += __shfl_xor(p, off);
    __shared__ float red[4];
    if ((tid & 63) == 0) red[tid >> 6] = p;
    __syncthreads();
    if (tid == 0) out[b] = 1.f / (1.f + expf(-(red[0] + red[1] + red[2] + red[3] + bc[0])));
}

// ---------------- launch ----------------

extern "C" void kernel_launch(void* const* d_in, const int* in_sizes, int n_in,
                              void* d_out, int out_size, void* d_ws, size_t ws_size,
                              hipStream_t stream) {
    const float* X_seq  = (const float*)d_in[0];
    const float* Wh     = (const float*)d_in[1];
    const float* bh_lin = (const float*)d_in[2];
    const float* Wx     = (const float*)d_in[3];
    const float* bx_lin = (const float*)d_in[4];
    const float* Wst    = (const float*)d_in[5];
    const float* bst    = (const float*)d_in[6];
    const float* Ws     = (const float*)d_in[7];
    const float* bs_lin = (const float*)d_in[8];
    const float* bg     = (const float*)d_in[9];
    const float* Waq    = (const float*)d_in[10];
    const float* baq    = (const float*)d_in[11];
    const float* Wah    = (const float*)d_in[12];
    const float* bah    = (const float*)d_in[13];
    const float* vt     = (const float*)d_in[14];
    const float* W_h    = (const float*)d_in[15];
    const float* b_Wh   = (const float*)d_in[16];
    const float* We     = (const float*)d_in[17];
    const float* b_We   = (const float*)d_in[18];
    const float* Wg     = (const float*)d_in[19];
    const float* b_Wg   = (const float*)d_in[20];
    const float* bh_p   = (const float*)d_in[21];
    const float* Wc     = (const float*)d_in[22];
    const float* bc     = (const float*)d_in[23];
    float* out = (float*)d_out;

    char* ws = (char*)d_ws;
    size_t off = 0;
    auto alloc = [&](size_t bytes) -> char* {
        char* p = ws + off;
        off = (off + bytes + 255) & ~(size_t)255;
        return p;
    };
    __hip_bfloat16* WA_shuf  = (__hip_bfloat16*)alloc((size_t)KKA * NH * 2);
    __hip_bfloat16* WB_shuf  = (__hip_bfloat16*)alloc((size_t)KKB * 5 * NH * 2);
    __hip_bfloat16* Wah_shuf = (__hip_bfloat16*)alloc((size_t)NH * NH * 2);
    float* bias_s   = (float*)alloc(NH * 4);
    float* bias_g   = (float*)alloc(5 * NH * 4);
    float* bias_fin = (float*)alloc(NH * 4);
    float* Dt       = (float*)alloc((size_t)NT * NB * 4);
    __hip_bfloat16* A_big = (__hip_bfloat16*)alloc((size_t)2 * NB * KKB * 2);
    float* c_last   = (float*)alloc((size_t)NB * NH * 4);
    float* s_f32    = (float*)alloc((size_t)NB * NH * 4);
    float* h_last   = (float*)alloc((size_t)NB * NH * 4);
    __hip_bfloat16* hist = (__hip_bfloat16*)alloc((size_t)NMEM * NB * NH * 2);
    float* qa       = (float*)alloc((size_t)NB * NH * 4);
    float* score_part = (float*)alloc((size_t)8 * NMEM * NB * 4);
    float* e_buf    = (float*)alloc((size_t)NB * NH * 4);
    float* h_fin    = (float*)alloc((size_t)NB * NH * 4);
    unsigned* bar   = (unsigned*)alloc((size_t)BAR_TOT * 4 + 4096);

    // prep (merged) + init
    hipLaunchKernelGGL(k_prep, dim3(6920), dim3(64), 0, stream,
                       Wh, Wx, Ws, Wah, bh_lin, bx_lin, bst, bs_lin, bg,
                       b_Wh, b_We, b_Wg, bh_p,
                       WA_shuf, WB_shuf, Wah_shuf, bias_s, bias_g, bias_fin);
    hipLaunchKernelGGL(k_init, dim3(NB), dim3(256), 0, stream, X_seq, Dt, A_big, bar);

    // persistent recurrent kernel (cooperative launch for co-residency guarantee)
    {
        void* args[] = {(void*)&X_seq, (void*)&Dt, (void*)&WA_shuf, (void*)&WB_shuf,
                        (void*)&bias_s, (void*)&bias_g, (void*)&Wst, (void*)&A_big,
                        (void*)&c_last, (void*)&s_f32, (void*)&h_last, (void*)&hist,
                        (void*)&bar};
        hipLaunchCooperativeKernel((void*)lstm_coop, dim3(256), dim3(256), args, 0, stream);
    }

    // attention + head
    hipLaunchKernelGGL(k_qa, dim3(32), dim3(512), 0, stream, h_last, c_last, Waq, baq, qa);
    hipLaunchKernelGGL(k_scores, dim3(512), dim3(256), 0, stream,
                       hist, Wah_shuf, qa, bah, vt, score_part);
    hipLaunchKernelGGL(k_softmax_e, dim3(NB), dim3(256), 0, stream, score_part, hist, e_buf);
    hipLaunchKernelGGL(k_final, dim3(64), dim3(512), 0, stream,
                       h_last, e_buf, X_seq, W_h, We, Wg, bias_fin, h_fin);
    hipLaunchKernelGGL(k_out, dim3(NB), dim3(256), 0, stream, h_fin, Wc, bc, out);
}